// Round 7
// baseline (343.633 us; speedup 1.0000x reference)
//
#include <hip/hip_runtime.h>

#define N_NODES 100000
#define N_EDGES 300000
#define N_ETOT  400000   // E + N self-loops
#define NGRAPH  4096
#define HID     128
#define NBLK_SCAN 391    // cdiv(N_NODES, 256)
#define PNPB    32       // nodes per block in pool
#define STATS_BLOCKS 512
#define NSLICE  16       // BN-stats atomic slices (16KB/layer table, read by consumers)

typedef __attribute__((ext_vector_type(8))) short short8;
typedef __attribute__((ext_vector_type(8))) ushort ushort8;
typedef __attribute__((ext_vector_type(4))) float f32x4;

__device__ __forceinline__ ushort f2bf(float f) {
    union { float f; unsigned u; } x; x.f = f;
    unsigned r = x.u + 0x7FFF + ((x.u >> 16) & 1);   // round-to-nearest-even
    return (ushort)(r >> 16);
}

__device__ __forceinline__ float bf2f(ushort v) {
    union { unsigned u; float f; } t;
    t.u = ((unsigned)v) << 16;
    return t.f;
}

// unpack uint holding 2 bf16 (channels 2k, 2k+1) -> float2
__device__ __forceinline__ float2 bf2f2(unsigned v) {
    union { unsigned u; float f; } lo, hi;
    lo.u = v << 16;
    hi.u = v & 0xFFFF0000u;
    return make_float2(lo.f, hi.f);
}

// ---------------- fused setup: weight converts + all zero-inits ----------------
#define SETUP_W      36864                       // Wt2 (16384) + Wt3 (16384) + Wt1 (4096)
#define SETUP_SUMS   (SETUP_W + 3 * NSLICE * 256)
#define SETUP_CNTS   (SETUP_SUMS + N_NODES)
#define SETUP_TOT    (SETUP_CNTS + NGRAPH * HID + NGRAPH)
__global__ __launch_bounds__(256) void setup_kernel(
    const float* __restrict__ W1, const float* __restrict__ W2, const float* __restrict__ W3,
    ushort* __restrict__ Wt1, ushort* __restrict__ Wt2, ushort* __restrict__ Wt3,
    float* __restrict__ sums_base, int* __restrict__ counts,
    float* __restrict__ pooled)
{
    const int i = blockIdx.x * 256 + threadIdx.x;
    if (i < 16384) {
        int c = i >> 7, k = i & 127;
        Wt2[c * 128 + k] = f2bf(W2[k * 128 + c]);
    } else if (i < 32768) {
        int j = i - 16384; int c = j >> 7, k = j & 127;
        Wt3[c * 128 + k] = f2bf(W3[k * 128 + c]);
    } else if (i < SETUP_W) {
        int j = i - 32768; int c = j >> 5, k = j & 31;
        Wt1[c * 32 + k] = (k < 22) ? f2bf(W1[k * 128 + c]) : (ushort)0;
    } else if (i < SETUP_SUMS) {
        sums_base[i - SETUP_W] = 0.f;
    } else if (i < SETUP_CNTS) {
        counts[i - SETUP_SUMS] = 0;
    } else if (i < SETUP_TOT) {
        pooled[i - SETUP_CNTS] = 0.f;
    }
}

// ---------------- MFMA GEMM: Cb[M,128](bf16) = act(A)[M,K]@W + fused scores ----------
// Whole-K staging: one global->LDS phase (all loads in flight together), XOR-swizzled
// LDS layout (conflict-free reads, no padding), ONE barrier before the MFMA loop.
// PRE_BN: scale/shift computed in-kernel from the raw BN slice table (finalize folded).
// DX=true: stage A directly from f32 x [N,22], converting+padding to bf16 [.,32].
template<int K, bool PRE_BN, int HH, bool DX>
__global__ __launch_bounds__(256) void mfma_gemm_kernel(
    const ushort* __restrict__ Ab, const float* __restrict__ Af,
    const ushort* __restrict__ Wt,
    const float* __restrict__ sums, const float* __restrict__ g, const float* __restrict__ be,
    const float* __restrict__ avs, const float* __restrict__ avd,
    ushort* __restrict__ Cb, float* __restrict__ als, float* __restrict__ ald, int M)
{
    constexpr int SEGS = K / 8;               // 16B segments per row
    constexpr int SSH  = (K == 128) ? 4 : 2;  // log2(SEGS)
    constexpr int SWM  = SEGS - 1;            // swizzle mask
    constexpr int NP   = SEGS / 2;            // staging passes (256 thr, 128 rows)
    constexpr int KT   = K / 32;              // 32-wide k subtiles

    __shared__ ushort Asm[128 * K];           // K=128: 32 KB each -> 64 KB total
    __shared__ ushort Bsm[128 * K];
    __shared__ float scsh[256];               // [0..127]=scale, [128..255]=shift

    const int tid  = threadIdx.x;
    const int wave = tid >> 6;
    const int lane = tid & 63;
    const int ln   = lane & 15;
    const int quad = lane >> 4;
    const int wr0  = (wave >> 1) * 64;
    const int wc0  = (wave & 1) * 64;
    const int row0 = blockIdx.x * 128;

    // ---- staging: issue ALL global loads first (max MLP), then store swizzled ----
    short8 aR[NP], wR[NP];
    #pragma unroll
    for (int q = 0; q < NP; ++q) {
        const int chunk = tid + q * 256;
        const int r   = chunk >> SSH;
        const int seg = chunk & SWM;
        if constexpr (DX) {
            const int rr = min(row0 + r, N_NODES - 1);   // clamp: x has exactly N rows
            #pragma unroll
            for (int i = 0; i < 8; ++i) {
                const int c = seg * 8 + i;
                const float f = (c < 22) ? Af[(size_t)rr * 22 + c] : 0.f;
                aR[q][i] = (short)f2bf(f);
            }
        } else {
            aR[q] = *(const short8*)&Ab[(size_t)(row0 + r) * K + seg * 8];
        }
        wR[q] = *(const short8*)&Wt[(size_t)r * K + seg * 8];
    }
    if constexpr (PRE_BN) {
        // fold bn_finalize: reduce slice table -> scale/shift (while loads in flight)
        if (tid < 128) {
            float s = 0.f, q2 = 0.f;
            for (int b = 0; b < NSLICE; ++b) {
                s  += sums[b * 256 + tid];
                q2 += sums[b * 256 + 128 + tid];
            }
            const float m  = s * (1.f / N_NODES);
            const float v  = q2 * (1.f / N_NODES) - m * m;
            const float sc = g[tid] * rsqrtf(v + 1e-5f);
            scsh[tid]       = sc;
            scsh[tid + 128] = be[tid] - m * sc;
        }
        __syncthreads();
        #pragma unroll
        for (int q = 0; q < NP; ++q) {
            const int seg = (tid + q * 256) & SWM;
            const int cc  = seg * 8;
            #pragma unroll
            for (int i = 0; i < 8; ++i) {
                float f = bf2f((ushort)aR[q][i]);
                f = fmaxf(f * scsh[cc + i] + scsh[128 + cc + i], 0.f);
                aR[q][i] = (short)f2bf(f);
            }
        }
    }
    #pragma unroll
    for (int q = 0; q < NP; ++q) {
        const int chunk = tid + q * 256;
        const int r   = chunk >> SSH;
        const int seg = chunk & SWM;
        const int sp  = seg ^ (r & SWM);
        *(short8*)&Asm[r * K + sp * 8] = aR[q];
        *(short8*)&Bsm[r * K + sp * 8] = wR[q];
    }
    __syncthreads();

    // ---- MFMA loop: no barriers, all data LDS-resident ----
    f32x4 acc[4][4] = {};
    #pragma unroll
    for (int kt = 0; kt < KT; ++kt) {
        short8 af[4], bf[4];
        #pragma unroll
        for (int i = 0; i < 4; ++i) {
            const int ra = wr0 + i * 16 + ln;
            const int ca = wc0 + i * 16 + ln;
            af[i] = *(const short8*)&Asm[ra * K + (((kt * 4 + quad) ^ (ra & SWM)) * 8)];
            bf[i] = *(const short8*)&Bsm[ca * K + (((kt * 4 + quad) ^ (ca & SWM)) * 8)];
        }
        #pragma unroll
        for (int tr = 0; tr < 4; ++tr)
            #pragma unroll
            for (int tc = 0; tc < 4; ++tc)
                acc[tr][tc] = __builtin_amdgcn_mfma_f32_16x16x32_bf16(
                    af[tr], bf[tc], acc[tr][tc], 0, 0, 0);
    }

    // ---- C write (bf16; C/D layout: col=lane&15, row=quad*4+reg) ----
    #pragma unroll
    for (int tr = 0; tr < 4; ++tr)
        #pragma unroll
        for (int rg = 0; rg < 4; ++rg) {
            const int gr = row0 + wr0 + tr * 16 + quad * 4 + rg;
            if (gr < M) {
                #pragma unroll
                for (int tc = 0; tc < 4; ++tc)
                    Cb[(size_t)gr * HID + wc0 + tc * 16 + ln] = f2bf(acc[tr][tc][rg]);
            }
        }

    // ---- fused attention scores (ps/pd alias Asm/Bsm after all ds_reads done) ----
    __syncthreads();
    float* ps = (float*)Asm;   // [128][4]
    float* pd = (float*)Bsm;
    #pragma unroll
    for (int tr = 0; tr < 4; ++tr)
      #pragma unroll
      for (int rg = 0; rg < 4; ++rg) {
        float sA = 0.f, sB = 0.f, dA = 0.f, dB = 0.f;
        #pragma unroll
        for (int tc = 0; tc < 4; ++tc) {
            const int col = wc0 + tc * 16 + ln;
            const float v = acc[tr][tc][rg];
            if (tc < 2) { sA += v * avs[col]; dA += v * avd[col]; }
            else        { sB += v * avs[col]; dB += v * avd[col]; }
        }
        #pragma unroll
        for (int m = 1; m < 16; m <<= 1) {
            sA += __shfl_xor(sA, m); sB += __shfl_xor(sB, m);
            dA += __shfl_xor(dA, m); dB += __shfl_xor(dB, m);
        }
        if (ln == 0) {
            const int rl = wr0 + tr * 16 + quad * 4 + rg;
            const int h0 = (wave & 1) * 2;
            ps[rl * 4 + h0] = sA; ps[rl * 4 + h0 + 1] = sB;
            pd[rl * 4 + h0] = dA; pd[rl * 4 + h0 + 1] = dB;
        }
      }
    __syncthreads();
    {
        const int r  = tid & 127;
        const int gr = row0 + r;
        if (gr < M) {
            if (tid < 128) {
                if (HH == 4) {
                    #pragma unroll
                    for (int h = 0; h < 4; ++h) als[gr * 4 + h] = ps[r * 4 + h];
                } else als[gr] = ps[r * 4] + ps[r * 4 + 1] + ps[r * 4 + 2] + ps[r * 4 + 3];
            } else {
                if (HH == 4) {
                    #pragma unroll
                    for (int h = 0; h < 4; ++h) ald[gr * 4 + h] = pd[r * 4 + h];
                } else ald[gr] = pd[r * 4] + pd[r * 4 + 1] + pd[r * 4 + 2] + pd[r * 4 + 3];
            }
        }
    }
}

// ---------------- CSR build ----------------
__global__ void hist_kernel(const int* __restrict__ ei, int* __restrict__ counts) {
    int e = blockIdx.x * blockDim.x + threadIdx.x;
    if (e >= N_ETOT) return;
    int dst = (e < N_EDGES) ? ei[N_EDGES + e] : e - N_EDGES;
    atomicAdd(&counts[dst], 1);
}

__global__ __launch_bounds__(256) void scanA_kernel(
    const int* __restrict__ counts, int* __restrict__ rowptr, int* __restrict__ bsum)
{
    __shared__ int ls[256];
    const int t = threadIdx.x;
    const int i = blockIdx.x * 256 + t;
    const int v = (i < N_NODES) ? counts[i] : 0;
    ls[t] = v; __syncthreads();
    #pragma unroll
    for (int off = 1; off < 256; off <<= 1) {
        int add = (t >= off) ? ls[t - off] : 0;
        __syncthreads();
        ls[t] += add;
        __syncthreads();
    }
    if (i < N_NODES) rowptr[i] = ls[t] - v;
    if (t == 255) bsum[blockIdx.x] = ls[255];
}

// scanB folded in: each block redundantly sums bsum[0..bid-1] (1.5 KB, trivial)
__global__ __launch_bounds__(256) void scanC_kernel(
    int* __restrict__ rowptr, const int* __restrict__ bsum, int* __restrict__ cursor)
{
    __shared__ int red[256];
    const int t = threadIdx.x;
    int s = 0;
    for (int b = t; b < (int)blockIdx.x; b += 256) s += bsum[b];
    red[t] = s;
    __syncthreads();
    #pragma unroll
    for (int off = 128; off; off >>= 1) {
        if (t < off) red[t] += red[t + off];
        __syncthreads();
    }
    const int base = red[0];
    const int i = blockIdx.x * 256 + t;
    if (i < N_NODES) {
        const int v = rowptr[i] + base;
        rowptr[i] = v;
        cursor[i] = v;
    }
    if (i == 0) rowptr[N_NODES] = N_ETOT;
}

__global__ void scatter_kernel(const int* __restrict__ ei, int* __restrict__ cursor,
                               int* __restrict__ psrc)
{
    int e = blockIdx.x * blockDim.x + threadIdx.x;
    if (e >= N_ETOT) return;
    int src, dst;
    if (e < N_EDGES) { src = ei[e]; dst = ei[N_EDGES + e]; }
    else             { src = dst = e - N_EDGES; }
    int pos = atomicAdd(&cursor[dst], 1);
    psrc[pos] = src;
}

// ------- single-pass softmax aggregation: 2 nodes/wave, edge loop unrolled x2 -------
// 4 gather streams per lane-iteration (2 nodes x 2 edges) for max memory-level
// parallelism; accumulators unchanged (VGPR stays under the 64 cliff). Branchless
// clamped loads (valid: every node has a self-loop); inactive edges contribute exact
// 0.f, and the unrolled add order (p then p+4, stride 8) matches the stride-4 loop
// sequence -> bitwise identical per-node results.
template<int HH>
__global__ __launch_bounds__(256) void agg_kernel(
    const ushort* __restrict__ H, const float* __restrict__ als,
    const float* __restrict__ ald, const int* __restrict__ rowptr,
    const int* __restrict__ psrc, ushort* __restrict__ Outb)
{
    const int tid   = threadIdx.x;
    const int w     = tid >> 6;
    const int lane  = tid & 63;
    const int grp   = lane >> 4;       // edge slot 0..3
    const int cl    = lane & 15;       // channels 8*cl .. 8*cl+7
    const int hd    = (HH == 4) ? (cl >> 2) : 0;
    const int nodeA = blockIdx.x * 8 + w * 2;   // grid exact: 12500*8 = N_NODES
    const int nodeB = nodeA + 1;

    const int r0A = rowptr[nodeA];
    const int r1A = rowptr[nodeA + 1];          // == r0B
    const int r1B = rowptr[nodeB + 1];
    const float aldA = (HH == 4) ? ald[nodeA * 4 + hd] : ald[nodeA];
    const float aldB = (HH == 4) ? ald[nodeB * 4 + hd] : ald[nodeB];

    float denA = 0.f, denB = 0.f;
    float accA[8] = {}, accB[8] = {};
    int pA = r0A + grp;
    int pB = r1A + grp;
    while (pA < r1A || pB < r1B) {
        const bool aA0 = pA < r1A,      aA1 = pA + 4 < r1A;
        const bool aB0 = pB < r1B,      aB1 = pB + 4 < r1B;
        const int qA0 = aA0 ? pA     : (r1A - 1);   // always-valid clamp (deg>=1)
        const int qA1 = aA1 ? pA + 4 : (r1A - 1);
        const int qB0 = aB0 ? pB     : (r1B - 1);
        const int qB1 = aB1 ? pB + 4 : (r1B - 1);
        const int sA0 = psrc[qA0], sA1 = psrc[qA1];
        const int sB0 = psrc[qB0], sB1 = psrc[qB1];
        const float svA0 = (HH == 4) ? als[sA0 * 4 + hd] : als[sA0];
        const float svA1 = (HH == 4) ? als[sA1 * 4 + hd] : als[sA1];
        const float svB0 = (HH == 4) ? als[sB0 * 4 + hd] : als[sB0];
        const float svB1 = (HH == 4) ? als[sB1 * 4 + hd] : als[sB1];
        const uint4 hvA0 = *(const uint4*)&H[(size_t)sA0 * HID + cl * 8];
        const uint4 hvA1 = *(const uint4*)&H[(size_t)sA1 * HID + cl * 8];
        const uint4 hvB0 = *(const uint4*)&H[(size_t)sB0 * HID + cl * 8];
        const uint4 hvB1 = *(const uint4*)&H[(size_t)sB1 * HID + cl * 8];

        float vA0 = svA0 + aldA; vA0 = (vA0 > 0.f) ? vA0 : 0.2f * vA0;
        float vA1 = svA1 + aldA; vA1 = (vA1 > 0.f) ? vA1 : 0.2f * vA1;
        float vB0 = svB0 + aldB; vB0 = (vB0 > 0.f) ? vB0 : 0.2f * vB0;
        float vB1 = svB1 + aldB; vB1 = (vB1 > 0.f) ? vB1 : 0.2f * vB1;
        const float exA0 = aA0 ? __expf(vA0) : 0.f;
        const float exA1 = aA1 ? __expf(vA1) : 0.f;
        const float exB0 = aB0 ? __expf(vB0) : 0.f;
        const float exB1 = aB1 ? __expf(vB1) : 0.f;
        {   // node A, edge p (then p+4) -- order matches the stride-4 loop
            const float2 h0 = bf2f2(hvA0.x), h1 = bf2f2(hvA0.y);
            const float2 h2 = bf2f2(hvA0.z), h3 = bf2f2(hvA0.w);
            accA[0] += exA0 * h0.x; accA[1] += exA0 * h0.y;
            accA[2] += exA0 * h1.x; accA[3] += exA0 * h1.y;
            accA[4] += exA0 * h2.x; accA[5] += exA0 * h2.y;
            accA[6] += exA0 * h3.x; accA[7] += exA0 * h3.y;
            denA += exA0;
        }
        {
            const float2 h0 = bf2f2(hvA1.x), h1 = bf2f2(hvA1.y);
            const float2 h2 = bf2f2(hvA1.z), h3 = bf2f2(hvA1.w);
            accA[0] += exA1 * h0.x; accA[1] += exA1 * h0.y;
            accA[2] += exA1 * h1.x; accA[3] += exA1 * h1.y;
            accA[4] += exA1 * h2.x; accA[5] += exA1 * h2.y;
            accA[6] += exA1 * h3.x; accA[7] += exA1 * h3.y;
            denA += exA1;
        }
        {
            const float2 h0 = bf2f2(hvB0.x), h1 = bf2f2(hvB0.y);
            const float2 h2 = bf2f2(hvB0.z), h3 = bf2f2(hvB0.w);
            accB[0] += exB0 * h0.x; accB[1] += exB0 * h0.y;
            accB[2] += exB0 * h1.x; accB[3] += exB0 * h1.y;
            accB[4] += exB0 * h2.x; accB[5] += exB0 * h2.y;
            accB[6] += exB0 * h3.x; accB[7] += exB0 * h3.y;
            denB += exB0;
        }
        {
            const float2 h0 = bf2f2(hvB1.x), h1 = bf2f2(hvB1.y);
            const float2 h2 = bf2f2(hvB1.z), h3 = bf2f2(hvB1.w);
            accB[0] += exB1 * h0.x; accB[1] += exB1 * h0.y;
            accB[2] += exB1 * h1.x; accB[3] += exB1 * h1.y;
            accB[4] += exB1 * h2.x; accB[5] += exB1 * h2.y;
            accB[6] += exB1 * h3.x; accB[7] += exB1 * h3.y;
            denB += exB1;
        }
        pA += 8; pB += 8;
    }
    #pragma unroll
    for (int m = 16; m < 64; m <<= 1) {
        denA += __shfl_xor(denA, m);
        denB += __shfl_xor(denB, m);
        #pragma unroll
        for (int i = 0; i < 8; ++i) {
            accA[i] += __shfl_xor(accA[i], m);
            accB[i] += __shfl_xor(accB[i], m);
        }
    }
    if (grp == 0) {
        const float inv = 1.f / (denA + 1e-16f);
        ushort8 o;
        #pragma unroll
        for (int i = 0; i < 8; ++i) o[i] = f2bf(accA[i] * inv);
        *(ushort8*)&Outb[(size_t)nodeA * HID + cl * 8] = o;
    } else if (grp == 1) {
        const float inv = 1.f / (denB + 1e-16f);
        ushort8 o;
        #pragma unroll
        for (int i = 0; i < 8; ++i) o[i] = f2bf(accB[i] * inv);
        *(ushort8*)&Outb[(size_t)nodeB * HID + cl * 8] = o;
    }
}

// ---------------- BN stats: vectorized 16B loads, register accum, sliced atomics ----
__global__ __launch_bounds__(256) void bn_stats_kernel(
    const ushort* __restrict__ X, float* __restrict__ sums_sl)
{
    __shared__ float ls[16][128], lq[16][128];   // 16 KB
    const int tid = threadIdx.x;
    const int ro  = tid >> 4;         // row slice 0..15
    const int ci  = tid & 15;         // chunk of 8 channels
    const int c0  = ci * 8;
    const int rpb = (N_NODES + STATS_BLOCKS - 1) / STATS_BLOCKS;   // 196
    const int r0  = blockIdx.x * rpb;
    const int r1  = min(r0 + rpb, N_NODES);

    float s[8] = {}, q[8] = {};
    for (int r = r0 + ro; r < r1; r += 16) {
        const ushort8 v = *(const ushort8*)&X[(size_t)r * HID + c0];
        #pragma unroll
        for (int j = 0; j < 8; ++j) {
            const float f = bf2f(v[j]);
            s[j] += f; q[j] += f * f;
        }
    }
    #pragma unroll
    for (int j = 0; j < 8; ++j) { ls[ro][c0 + j] = s[j]; lq[ro][c0 + j] = q[j]; }
    __syncthreads();
    const int half = tid >> 7;
    const int c    = tid & 127;
    float acc = 0.f;
    if (half == 0) {
        #pragma unroll
        for (int k = 0; k < 16; ++k) acc += ls[k][c];
    } else {
        #pragma unroll
        for (int k = 0; k < 16; ++k) acc += lq[k][c];
    }
    atomicAdd(&sums_sl[(blockIdx.x & (NSLICE - 1)) * 256 + tid], acc);
}

// ---------------- layer-3 BN+ReLU fused pool (finalize folded; batch sorted) --------
__global__ __launch_bounds__(128) void bn_pool_kernel(
    const ushort* __restrict__ X,
    const float* __restrict__ sums, const float* __restrict__ g, const float* __restrict__ be,
    const int* __restrict__ batch, float* __restrict__ pooled, float* __restrict__ cnt)
{
    const int c = threadIdx.x;
    // fold bn_finalize: per-thread channel scale/shift from raw slice table
    float s = 0.f, q2 = 0.f;
    for (int b = 0; b < NSLICE; ++b) {
        s  += sums[b * 256 + c];
        q2 += sums[b * 256 + 128 + c];
    }
    const float m  = s * (1.f / N_NODES);
    const float vv = q2 * (1.f / N_NODES) - m * m;
    const float sc = g[c] * rsqrtf(vv + 1e-5f);
    const float sh = be[c] - m * sc;

    const int n0 = blockIdx.x * PNPB;
    const int n1 = min(n0 + PNPB, N_NODES);
    int gcur = batch[n0];
    float acc = 0.f;
    int run = 0;
    for (int n = n0; n < n1; ++n) {
        const int gg = batch[n];
        if (gg != gcur) {
            atomicAdd(&pooled[(size_t)gcur * HID + c], acc);
            if (c == 0) atomicAdd(&cnt[gcur], (float)run);
            acc = 0.f; run = 0; gcur = gg;
        }
        const float v = bf2f(X[(size_t)n * HID + c]) * sc + sh;
        acc += fmaxf(v, 0.f);
        ++run;
    }
    atomicAdd(&pooled[(size_t)gcur * HID + c], acc);
    if (c == 0) atomicAdd(&cnt[gcur], (float)run);
}

// ---------------- MLP head ----------------
__global__ __launch_bounds__(256) void mlp_kernel(
    const float* __restrict__ pooled, const float* __restrict__ cnt,
    const float* __restrict__ fw1, const float* __restrict__ fb1,
    const float* __restrict__ fw2, const float* __restrict__ fb2,
    float* __restrict__ out)
{
    __shared__ float w1[HID * 64];
    __shared__ float rows[4][HID];
    const int tid = threadIdx.x;
    for (int i = tid; i < HID * 64; i += 256) w1[i] = fw1[i];
    const int gl = tid >> 6;
    const int j  = tid & 63;
    const float b1 = fb1[j];
    const float w2 = fw2[j];
    __syncthreads();
    #pragma unroll
    for (int it = 0; it < 4; ++it) {
        const int g = blockIdx.x * 16 + it * 4 + gl;
        const float inv = 1.f / fmaxf(cnt[g], 1.f);
        rows[gl][j]      = pooled[(size_t)g * HID + j] * inv;
        rows[gl][j + 64] = pooled[(size_t)g * HID + 64 + j] * inv;
        __syncthreads();
        float z = b1;
        #pragma unroll 8
        for (int c2 = 0; c2 < HID; ++c2) z += rows[gl][c2] * w1[c2 * 64 + j];
        z = fmaxf(z, 0.f);
        float p = z * w2;
        #pragma unroll
        for (int off = 32; off; off >>= 1) p += __shfl_down(p, off);
        if (j == 0) out[g] = p + fb2[0];
        __syncthreads();
    }
}

// ---------------- host ----------------
extern "C" void kernel_launch(void* const* d_in, const int* in_sizes, int n_in,
                              void* d_out, int out_size, void* d_ws, size_t ws_size,
                              hipStream_t stream)
{
    const float* x     = (const float*)d_in[0];
    const int*   ei    = (const int*)d_in[1];
    const int*   batch = (const int*)d_in[2];
    const float* W1  = (const float*)d_in[3];
    const float* as1 = (const float*)d_in[4];
    const float* ad1 = (const float*)d_in[5];
    const float* g1  = (const float*)d_in[7];
    const float* be1 = (const float*)d_in[8];
    const float* W2  = (const float*)d_in[9];
    const float* as2 = (const float*)d_in[10];
    const float* ad2 = (const float*)d_in[11];
    const float* g2  = (const float*)d_in[13];
    const float* be2 = (const float*)d_in[14];
    const float* W3  = (const float*)d_in[15];
    const float* as3 = (const float*)d_in[16];
    const float* ad3 = (const float*)d_in[17];
    const float* g3  = (const float*)d_in[19];
    const float* be3 = (const float*)d_in[20];
    const float* fw1 = (const float*)d_in[21];
    const float* fb1 = (const float*)d_in[22];
    const float* fw2 = (const float*)d_in[23];
    const float* fb2 = (const float*)d_in[24];
    float* out = (float*)d_out;

    // ---- ws layout ----
    ushort* Hb  = (ushort*)d_ws;                       // [N][128] bf16 GEMM output
    ushort* Bh  = Hb  + (size_t)N_NODES * HID;         // [N][128] bf16 aggregated
    ushort* Wt1 = Bh  + (size_t)N_NODES * HID + 128 * 128;  // pad: gemm stages OOB rows
    ushort* Wt2 = Wt1 + 128 * 32;                      // [128][128]
    ushort* Wt3 = Wt2 + 128 * 128;
    float* als    = (float*)(Wt3 + 128 * 128);
    float* ald    = als + (size_t)N_NODES * 4;
    float* sums1  = ald + (size_t)N_NODES * 4;         // 3 x [NSLICE][256]
    float* sums2  = sums1 + NSLICE * 256;
    float* sums3  = sums2 + NSLICE * 256;
    float* pooled = sums3 + NSLICE * 256;
    float* cnt    = pooled + (size_t)NGRAPH * HID;     // pooled+cnt contiguous
    int*   rowptr = (int*)(cnt + NGRAPH);
    int*   counts = rowptr + (N_NODES + 1);
    int*   cursor = counts + N_NODES;
    int*   bsum   = cursor + N_NODES;
    int*   psrc   = bsum + 512;

    auto cdiv = [](int a, int b) { return (a + b - 1) / b; };

    // ---- fused setup (weight converts + zero-inits, one dispatch) ----
    setup_kernel<<<cdiv(SETUP_TOT, 256), 256, 0, stream>>>(
        W1, W2, W3, Wt1, Wt2, Wt3, sums1, counts, pooled);

    // ---- CSR build (once) ----
    hist_kernel<<<cdiv(N_ETOT, 256), 256, 0, stream>>>(ei, counts);
    scanA_kernel<<<NBLK_SCAN, 256, 0, stream>>>(counts, rowptr, bsum);
    scanC_kernel<<<NBLK_SCAN, 256, 0, stream>>>(rowptr, bsum, cursor);
    scatter_kernel<<<cdiv(N_ETOT, 256), 256, 0, stream>>>(ei, cursor, psrc);

    const int ggrid = cdiv(N_NODES, 128);
    const int agrid = N_NODES / 8;   // 12500, exact (8 nodes per block, 2 per wave)

    // ---- layer 1: K=32 (padded), stage directly from f32 x, 4 heads ----
    mfma_gemm_kernel<32, false, 4, true><<<ggrid, 256, 0, stream>>>(
        nullptr, x, Wt1, nullptr, nullptr, nullptr, as1, ad1, Hb, als, ald, N_NODES);
    agg_kernel<4><<<agrid, 256, 0, stream>>>(Hb, als, ald, rowptr, psrc, Bh);
    bn_stats_kernel<<<STATS_BLOCKS, 256, 0, stream>>>(Bh, sums1);

    // ---- layer 2: K=128, BN(sums1,g1,be1) folded into staging, 4 heads ----
    mfma_gemm_kernel<128, true, 4, false><<<ggrid, 256, 0, stream>>>(
        Bh, nullptr, Wt2, sums1, g1, be1, as2, ad2, Hb, als, ald, N_NODES);
    agg_kernel<4><<<agrid, 256, 0, stream>>>(Hb, als, ald, rowptr, psrc, Bh);
    bn_stats_kernel<<<STATS_BLOCKS, 256, 0, stream>>>(Bh, sums2);

    // ---- layer 3: K=128, BN(sums2,g2,be2) folded into staging, 1 head ----
    mfma_gemm_kernel<128, true, 1, false><<<ggrid, 256, 0, stream>>>(
        Bh, nullptr, Wt3, sums2, g2, be2, as3, ad3, Hb, als, ald, N_NODES);
    agg_kernel<1><<<agrid, 256, 0, stream>>>(Hb, als, ald, rowptr, psrc, Bh);
    bn_stats_kernel<<<STATS_BLOCKS, 256, 0, stream>>>(Bh, sums3);

    // ---- BN(sums3,g3,be3)+ReLU fused pool, then MLP ----
    bn_pool_kernel<<<cdiv(N_NODES, PNPB), 128, 0, stream>>>(
        Bh, sums3, g3, be3, batch, pooled, cnt);
    mlp_kernel<<<NGRAPH / 16, 256, 0, stream>>>(pooled, cnt, fw1, fb1, fw2, fb2, out);
}

// Round 8
// 339.579 us; speedup vs baseline: 1.0119x; 1.0119x over previous
//
#include <hip/hip_runtime.h>

#define N_NODES 100000
#define N_EDGES 300000
#define N_ETOT  400000   // E + N self-loops
#define NGRAPH  4096
#define HID     128
#define NBLK_SCAN 391    // cdiv(N_NODES, 256)
#define PNPB    32       // nodes per block in pool
#define STATS_BLOCKS 512
#define NSLICE  16       // BN-stats atomic slices (16KB/layer table, read by consumers)

typedef __attribute__((ext_vector_type(8))) short short8;
typedef __attribute__((ext_vector_type(8))) ushort ushort8;
typedef __attribute__((ext_vector_type(4))) float f32x4;

__device__ __forceinline__ ushort f2bf(float f) {
    union { float f; unsigned u; } x; x.f = f;
    unsigned r = x.u + 0x7FFF + ((x.u >> 16) & 1);   // round-to-nearest-even
    return (ushort)(r >> 16);
}

__device__ __forceinline__ float bf2f(ushort v) {
    union { unsigned u; float f; } t;
    t.u = ((unsigned)v) << 16;
    return t.f;
}

// unpack uint holding 2 bf16 (channels 2k, 2k+1) -> float2
__device__ __forceinline__ float2 bf2f2(unsigned v) {
    union { unsigned u; float f; } lo, hi;
    lo.u = v << 16;
    hi.u = v & 0xFFFF0000u;
    return make_float2(lo.f, hi.f);
}

// ---------------- fused setup: weight converts + all zero-inits ----------------
#define SETUP_W      36864                       // Wt2 (16384) + Wt3 (16384) + Wt1 (4096)
#define SETUP_SUMS   (SETUP_W + 3 * NSLICE * 256)
#define SETUP_CNTS   (SETUP_SUMS + N_NODES)
#define SETUP_TOT    (SETUP_CNTS + NGRAPH * HID + NGRAPH)
__global__ __launch_bounds__(256) void setup_kernel(
    const float* __restrict__ W1, const float* __restrict__ W2, const float* __restrict__ W3,
    ushort* __restrict__ Wt1, ushort* __restrict__ Wt2, ushort* __restrict__ Wt3,
    float* __restrict__ sums_base, int* __restrict__ counts,
    float* __restrict__ pooled)
{
    const int i = blockIdx.x * 256 + threadIdx.x;
    if (i < 16384) {
        int c = i >> 7, k = i & 127;
        Wt2[c * 128 + k] = f2bf(W2[k * 128 + c]);
    } else if (i < 32768) {
        int j = i - 16384; int c = j >> 7, k = j & 127;
        Wt3[c * 128 + k] = f2bf(W3[k * 128 + c]);
    } else if (i < SETUP_W) {
        int j = i - 32768; int c = j >> 5, k = j & 31;
        Wt1[c * 32 + k] = (k < 22) ? f2bf(W1[k * 128 + c]) : (ushort)0;
    } else if (i < SETUP_SUMS) {
        sums_base[i - SETUP_W] = 0.f;
    } else if (i < SETUP_CNTS) {
        counts[i - SETUP_SUMS] = 0;
    } else if (i < SETUP_TOT) {
        pooled[i - SETUP_CNTS] = 0.f;
    }
}

// ---------------- MFMA GEMM: Cb[M,128](bf16) = act(A)[M,K]@W + fused scores ----------
// A: whole-K staged in XOR-swizzled LDS (one barrier). W (B operand): each wave's 16
// fragments PRELOADED INTO REGISTERS during the staging phase (batched with A-loads,
// L2-hot, one waitcnt) -- values bitwise identical to the old Bsm roundtrip, but LDS
// halves (65->33 KB) so 3 blocks/CU instead of 2 (kernel was latency-bound at 15% occ).
// NOTE: r3's regression loaded W from global INSIDE the MFMA loop (per-kt L2 latency on
// the critical path); here the loads are hoisted into the staging shadow.
// PRE_BN: scale/shift computed in-kernel from the raw BN slice table (finalize folded).
// DX=true: stage A directly from f32 x [N,22], converting+padding to bf16 [.,32].
template<int K, bool PRE_BN, int HH, bool DX>
__global__ __launch_bounds__(256, 3) void mfma_gemm_kernel(
    const ushort* __restrict__ Ab, const float* __restrict__ Af,
    const ushort* __restrict__ Wt,
    const float* __restrict__ sums, const float* __restrict__ g, const float* __restrict__ be,
    const float* __restrict__ avs, const float* __restrict__ avd,
    ushort* __restrict__ Cb, float* __restrict__ als, float* __restrict__ ald, int M)
{
    constexpr int SEGS = K / 8;               // 16B segments per row
    constexpr int SSH  = (K == 128) ? 4 : 2;  // log2(SEGS)
    constexpr int SWM  = SEGS - 1;            // swizzle mask
    constexpr int NP   = SEGS / 2;            // staging passes (256 thr, 128 rows)
    constexpr int KT   = K / 32;              // 32-wide k subtiles

    __shared__ ushort Asm[128 * K];           // K=128: 32 KB (A only; W in registers)
    __shared__ float scsh[256];               // [0..127]=scale, [128..255]=shift

    const int tid  = threadIdx.x;
    const int wave = tid >> 6;
    const int lane = tid & 63;
    const int ln   = lane & 15;
    const int quad = lane >> 4;
    const int wr0  = (wave >> 1) * 64;
    const int wc0  = (wave & 1) * 64;
    const int row0 = blockIdx.x * 128;

    // ---- staging: issue ALL global loads (A tile + this wave's W fragments) ----
    short8 aR[NP];
    short8 bReg[KT][4];
    #pragma unroll
    for (int q = 0; q < NP; ++q) {
        const int chunk = tid + q * 256;
        const int r   = chunk >> SSH;
        const int seg = chunk & SWM;
        if constexpr (DX) {
            const int rr = min(row0 + r, N_NODES - 1);   // clamp: x has exactly N rows
            #pragma unroll
            for (int i = 0; i < 8; ++i) {
                const int c = seg * 8 + i;
                const float f = (c < 22) ? Af[(size_t)rr * 22 + c] : 0.f;
                aR[q][i] = (short)f2bf(f);
            }
        } else {
            aR[q] = *(const short8*)&Ab[(size_t)(row0 + r) * K + seg * 8];
        }
    }
    #pragma unroll
    for (int kt = 0; kt < KT; ++kt)
        #pragma unroll
        for (int i = 0; i < 4; ++i) {
            const int ca = wc0 + i * 16 + ln;
            bReg[kt][i] = *(const short8*)&Wt[(size_t)ca * K + (kt * 4 + quad) * 8];
        }
    if constexpr (PRE_BN) {
        // fold bn_finalize: reduce slice table -> scale/shift (while loads in flight)
        if (tid < 128) {
            float s = 0.f, q2 = 0.f;
            for (int b = 0; b < NSLICE; ++b) {
                s  += sums[b * 256 + tid];
                q2 += sums[b * 256 + 128 + tid];
            }
            const float m  = s * (1.f / N_NODES);
            const float v  = q2 * (1.f / N_NODES) - m * m;
            const float sc = g[tid] * rsqrtf(v + 1e-5f);
            scsh[tid]       = sc;
            scsh[tid + 128] = be[tid] - m * sc;
        }
        __syncthreads();
        #pragma unroll
        for (int q = 0; q < NP; ++q) {
            const int seg = (tid + q * 256) & SWM;
            const int cc  = seg * 8;
            #pragma unroll
            for (int i = 0; i < 8; ++i) {
                float f = bf2f((ushort)aR[q][i]);
                f = fmaxf(f * scsh[cc + i] + scsh[128 + cc + i], 0.f);
                aR[q][i] = (short)f2bf(f);
            }
        }
    }
    #pragma unroll
    for (int q = 0; q < NP; ++q) {
        const int chunk = tid + q * 256;
        const int r   = chunk >> SSH;
        const int seg = chunk & SWM;
        const int sp  = seg ^ (r & SWM);
        *(short8*)&Asm[r * K + sp * 8] = aR[q];
    }
    __syncthreads();

    // ---- MFMA loop: A from LDS, B from registers ----
    f32x4 acc[4][4] = {};
    #pragma unroll
    for (int kt = 0; kt < KT; ++kt) {
        short8 af[4];
        #pragma unroll
        for (int i = 0; i < 4; ++i) {
            const int ra = wr0 + i * 16 + ln;
            af[i] = *(const short8*)&Asm[ra * K + (((kt * 4 + quad) ^ (ra & SWM)) * 8)];
        }
        #pragma unroll
        for (int tr = 0; tr < 4; ++tr)
            #pragma unroll
            for (int tc = 0; tc < 4; ++tc)
                acc[tr][tc] = __builtin_amdgcn_mfma_f32_16x16x32_bf16(
                    af[tr], bReg[kt][tc], acc[tr][tc], 0, 0, 0);
    }

    // ---- C write (bf16; C/D layout: col=lane&15, row=quad*4+reg) ----
    #pragma unroll
    for (int tr = 0; tr < 4; ++tr)
        #pragma unroll
        for (int rg = 0; rg < 4; ++rg) {
            const int gr = row0 + wr0 + tr * 16 + quad * 4 + rg;
            if (gr < M) {
                #pragma unroll
                for (int tc = 0; tc < 4; ++tc)
                    Cb[(size_t)gr * HID + wc0 + tc * 16 + ln] = f2bf(acc[tr][tc][rg]);
            }
        }

    // ---- fused attention scores (ps/pd alias Asm after all ds_reads done) ----
    __syncthreads();
    float* ps = (float*)Asm;   // [128][4] = 2KB
    float* pd = ps + 512;      // next 2KB (Asm >= 8KB even for K=32)
    #pragma unroll
    for (int tr = 0; tr < 4; ++tr)
      #pragma unroll
      for (int rg = 0; rg < 4; ++rg) {
        float sA = 0.f, sB = 0.f, dA = 0.f, dB = 0.f;
        #pragma unroll
        for (int tc = 0; tc < 4; ++tc) {
            const int col = wc0 + tc * 16 + ln;
            const float v = acc[tr][tc][rg];
            if (tc < 2) { sA += v * avs[col]; dA += v * avd[col]; }
            else        { sB += v * avs[col]; dB += v * avd[col]; }
        }
        #pragma unroll
        for (int m = 1; m < 16; m <<= 1) {
            sA += __shfl_xor(sA, m); sB += __shfl_xor(sB, m);
            dA += __shfl_xor(dA, m); dB += __shfl_xor(dB, m);
        }
        if (ln == 0) {
            const int rl = wr0 + tr * 16 + quad * 4 + rg;
            const int h0 = (wave & 1) * 2;
            ps[rl * 4 + h0] = sA; ps[rl * 4 + h0 + 1] = sB;
            pd[rl * 4 + h0] = dA; pd[rl * 4 + h0 + 1] = dB;
        }
      }
    __syncthreads();
    {
        const int r  = tid & 127;
        const int gr = row0 + r;
        if (gr < M) {
            if (tid < 128) {
                if (HH == 4) {
                    #pragma unroll
                    for (int h = 0; h < 4; ++h) als[gr * 4 + h] = ps[r * 4 + h];
                } else als[gr] = ps[r * 4] + ps[r * 4 + 1] + ps[r * 4 + 2] + ps[r * 4 + 3];
            } else {
                if (HH == 4) {
                    #pragma unroll
                    for (int h = 0; h < 4; ++h) ald[gr * 4 + h] = pd[r * 4 + h];
                } else ald[gr] = pd[r * 4] + pd[r * 4 + 1] + pd[r * 4 + 2] + pd[r * 4 + 3];
            }
        }
    }
}

// ---------------- CSR build ----------------
__global__ void hist_kernel(const int* __restrict__ ei, int* __restrict__ counts) {
    int e = blockIdx.x * blockDim.x + threadIdx.x;
    if (e >= N_ETOT) return;
    int dst = (e < N_EDGES) ? ei[N_EDGES + e] : e - N_EDGES;
    atomicAdd(&counts[dst], 1);
}

__global__ __launch_bounds__(256) void scanA_kernel(
    const int* __restrict__ counts, int* __restrict__ rowptr, int* __restrict__ bsum)
{
    __shared__ int ls[256];
    const int t = threadIdx.x;
    const int i = blockIdx.x * 256 + t;
    const int v = (i < N_NODES) ? counts[i] : 0;
    ls[t] = v; __syncthreads();
    #pragma unroll
    for (int off = 1; off < 256; off <<= 1) {
        int add = (t >= off) ? ls[t - off] : 0;
        __syncthreads();
        ls[t] += add;
        __syncthreads();
    }
    if (i < N_NODES) rowptr[i] = ls[t] - v;
    if (t == 255) bsum[blockIdx.x] = ls[255];
}

// scanB folded in: each block redundantly sums bsum[0..bid-1] (1.5 KB, trivial)
__global__ __launch_bounds__(256) void scanC_kernel(
    int* __restrict__ rowptr, const int* __restrict__ bsum, int* __restrict__ cursor)
{
    __shared__ int red[256];
    const int t = threadIdx.x;
    int s = 0;
    for (int b = t; b < (int)blockIdx.x; b += 256) s += bsum[b];
    red[t] = s;
    __syncthreads();
    #pragma unroll
    for (int off = 128; off; off >>= 1) {
        if (t < off) red[t] += red[t + off];
        __syncthreads();
    }
    const int base = red[0];
    const int i = blockIdx.x * 256 + t;
    if (i < N_NODES) {
        const int v = rowptr[i] + base;
        rowptr[i] = v;
        cursor[i] = v;
    }
    if (i == 0) rowptr[N_NODES] = N_ETOT;
}

__global__ void scatter_kernel(const int* __restrict__ ei, int* __restrict__ cursor,
                               int* __restrict__ psrc)
{
    int e = blockIdx.x * blockDim.x + threadIdx.x;
    if (e >= N_ETOT) return;
    int src, dst;
    if (e < N_EDGES) { src = ei[e]; dst = ei[N_EDGES + e]; }
    else             { src = dst = e - N_EDGES; }
    int pos = atomicAdd(&cursor[dst], 1);
    psrc[pos] = src;
}

// ------- single-pass softmax aggregation: 2 nodes per wave (2x memory-level par.) ----
// Pure, no LDS, no barriers. Branchless loads (clamped to r1-1, valid: every node has
// a self-loop) with inactive-edge contributions multiplied to exactly 0.f -> per-node
// accumulation order and butterfly identical to the 1-node/wave version (bitwise same).
template<int HH>
__global__ __launch_bounds__(256) void agg_kernel(
    const ushort* __restrict__ H, const float* __restrict__ als,
    const float* __restrict__ ald, const int* __restrict__ rowptr,
    const int* __restrict__ psrc, ushort* __restrict__ Outb)
{
    const int tid   = threadIdx.x;
    const int w     = tid >> 6;
    const int lane  = tid & 63;
    const int grp   = lane >> 4;       // edge slot 0..3
    const int cl    = lane & 15;       // channels 8*cl .. 8*cl+7
    const int hd    = (HH == 4) ? (cl >> 2) : 0;
    const int nodeA = blockIdx.x * 8 + w * 2;   // grid exact: 12500*8 = N_NODES
    const int nodeB = nodeA + 1;

    const int r0A = rowptr[nodeA];
    const int r1A = rowptr[nodeA + 1];          // == r0B
    const int r1B = rowptr[nodeB + 1];
    const float aldA = (HH == 4) ? ald[nodeA * 4 + hd] : ald[nodeA];
    const float aldB = (HH == 4) ? ald[nodeB * 4 + hd] : ald[nodeB];

    float denA = 0.f, denB = 0.f;
    float accA[8] = {}, accB[8] = {};
    int pA = r0A + grp;
    int pB = r1A + grp;
    while (pA < r1A || pB < r1B) {
        const bool aA = pA < r1A;
        const bool aB = pB < r1B;
        const int qA = aA ? pA : (r1A - 1);     // always-valid clamp (self-loop => deg>=1)
        const int qB = aB ? pB : (r1B - 1);
        const int sA = psrc[qA];
        const int sB = psrc[qB];
        const float svA = (HH == 4) ? als[sA * 4 + hd] : als[sA];
        const float svB = (HH == 4) ? als[sB * 4 + hd] : als[sB];
        const uint4 hvA = *(const uint4*)&H[(size_t)sA * HID + cl * 8];
        const uint4 hvB = *(const uint4*)&H[(size_t)sB * HID + cl * 8];

        float vA = svA + aldA; vA = (vA > 0.f) ? vA : 0.2f * vA;
        float vB = svB + aldB; vB = (vB > 0.f) ? vB : 0.2f * vB;
        const float exA = aA ? __expf(vA) : 0.f;
        const float exB = aB ? __expf(vB) : 0.f;
        {
            const float2 h0 = bf2f2(hvA.x), h1 = bf2f2(hvA.y);
            const float2 h2 = bf2f2(hvA.z), h3 = bf2f2(hvA.w);
            accA[0] += exA * h0.x; accA[1] += exA * h0.y;
            accA[2] += exA * h1.x; accA[3] += exA * h1.y;
            accA[4] += exA * h2.x; accA[5] += exA * h2.y;
            accA[6] += exA * h3.x; accA[7] += exA * h3.y;
            denA += exA;
        }
        {
            const float2 h0 = bf2f2(hvB.x), h1 = bf2f2(hvB.y);
            const float2 h2 = bf2f2(hvB.z), h3 = bf2f2(hvB.w);
            accB[0] += exB * h0.x; accB[1] += exB * h0.y;
            accB[2] += exB * h1.x; accB[3] += exB * h1.y;
            accB[4] += exB * h2.x; accB[5] += exB * h2.y;
            accB[6] += exB * h3.x; accB[7] += exB * h3.y;
            denB += exB;
        }
        pA += 4; pB += 4;
    }
    #pragma unroll
    for (int m = 16; m < 64; m <<= 1) {
        denA += __shfl_xor(denA, m);
        denB += __shfl_xor(denB, m);
        #pragma unroll
        for (int i = 0; i < 8; ++i) {
            accA[i] += __shfl_xor(accA[i], m);
            accB[i] += __shfl_xor(accB[i], m);
        }
    }
    if (grp == 0) {
        const float inv = 1.f / (denA + 1e-16f);
        ushort8 o;
        #pragma unroll
        for (int i = 0; i < 8; ++i) o[i] = f2bf(accA[i] * inv);
        *(ushort8*)&Outb[(size_t)nodeA * HID + cl * 8] = o;
    } else if (grp == 1) {
        const float inv = 1.f / (denB + 1e-16f);
        ushort8 o;
        #pragma unroll
        for (int i = 0; i < 8; ++i) o[i] = f2bf(accB[i] * inv);
        *(ushort8*)&Outb[(size_t)nodeB * HID + cl * 8] = o;
    }
}

// ---------------- BN stats: vectorized 16B loads, register accum, sliced atomics ----
__global__ __launch_bounds__(256) void bn_stats_kernel(
    const ushort* __restrict__ X, float* __restrict__ sums_sl)
{
    __shared__ float ls[16][128], lq[16][128];   // 16 KB
    const int tid = threadIdx.x;
    const int ro  = tid >> 4;         // row slice 0..15
    const int ci  = tid & 15;         // chunk of 8 channels
    const int c0  = ci * 8;
    const int rpb = (N_NODES + STATS_BLOCKS - 1) / STATS_BLOCKS;   // 196
    const int r0  = blockIdx.x * rpb;
    const int r1  = min(r0 + rpb, N_NODES);

    float s[8] = {}, q[8] = {};
    for (int r = r0 + ro; r < r1; r += 16) {
        const ushort8 v = *(const ushort8*)&X[(size_t)r * HID + c0];
        #pragma unroll
        for (int j = 0; j < 8; ++j) {
            const float f = bf2f(v[j]);
            s[j] += f; q[j] += f * f;
        }
    }
    #pragma unroll
    for (int j = 0; j < 8; ++j) { ls[ro][c0 + j] = s[j]; lq[ro][c0 + j] = q[j]; }
    __syncthreads();
    const int half = tid >> 7;
    const int c    = tid & 127;
    float acc = 0.f;
    if (half == 0) {
        #pragma unroll
        for (int k = 0; k < 16; ++k) acc += ls[k][c];
    } else {
        #pragma unroll
        for (int k = 0; k < 16; ++k) acc += lq[k][c];
    }
    atomicAdd(&sums_sl[(blockIdx.x & (NSLICE - 1)) * 256 + tid], acc);
}

// ---------------- layer-3 BN+ReLU fused pool (finalize folded; batch sorted) --------
__global__ __launch_bounds__(128) void bn_pool_kernel(
    const ushort* __restrict__ X,
    const float* __restrict__ sums, const float* __restrict__ g, const float* __restrict__ be,
    const int* __restrict__ batch, float* __restrict__ pooled, float* __restrict__ cnt)
{
    const int c = threadIdx.x;
    // fold bn_finalize: per-thread channel scale/shift from raw slice table
    float s = 0.f, q2 = 0.f;
    for (int b = 0; b < NSLICE; ++b) {
        s  += sums[b * 256 + c];
        q2 += sums[b * 256 + 128 + c];
    }
    const float m  = s * (1.f / N_NODES);
    const float vv = q2 * (1.f / N_NODES) - m * m;
    const float sc = g[c] * rsqrtf(vv + 1e-5f);
    const float sh = be[c] - m * sc;

    const int n0 = blockIdx.x * PNPB;
    const int n1 = min(n0 + PNPB, N_NODES);
    int gcur = batch[n0];
    float acc = 0.f;
    int run = 0;
    for (int n = n0; n < n1; ++n) {
        const int gg = batch[n];
        if (gg != gcur) {
            atomicAdd(&pooled[(size_t)gcur * HID + c], acc);
            if (c == 0) atomicAdd(&cnt[gcur], (float)run);
            acc = 0.f; run = 0; gcur = gg;
        }
        const float v = bf2f(X[(size_t)n * HID + c]) * sc + sh;
        acc += fmaxf(v, 0.f);
        ++run;
    }
    atomicAdd(&pooled[(size_t)gcur * HID + c], acc);
    if (c == 0) atomicAdd(&cnt[gcur], (float)run);
}

// ---------------- MLP head ----------------
__global__ __launch_bounds__(256) void mlp_kernel(
    const float* __restrict__ pooled, const float* __restrict__ cnt,
    const float* __restrict__ fw1, const float* __restrict__ fb1,
    const float* __restrict__ fw2, const float* __restrict__ fb2,
    float* __restrict__ out)
{
    __shared__ float w1[HID * 64];
    __shared__ float rows[4][HID];
    const int tid = threadIdx.x;
    for (int i = tid; i < HID * 64; i += 256) w1[i] = fw1[i];
    const int gl = tid >> 6;
    const int j  = tid & 63;
    const float b1 = fb1[j];
    const float w2 = fw2[j];
    __syncthreads();
    #pragma unroll
    for (int it = 0; it < 4; ++it) {
        const int g = blockIdx.x * 16 + it * 4 + gl;
        const float inv = 1.f / fmaxf(cnt[g], 1.f);
        rows[gl][j]      = pooled[(size_t)g * HID + j] * inv;
        rows[gl][j + 64] = pooled[(size_t)g * HID + 64 + j] * inv;
        __syncthreads();
        float z = b1;
        #pragma unroll 8
        for (int c2 = 0; c2 < HID; ++c2) z += rows[gl][c2] * w1[c2 * 64 + j];
        z = fmaxf(z, 0.f);
        float p = z * w2;
        #pragma unroll
        for (int off = 32; off; off >>= 1) p += __shfl_down(p, off);
        if (j == 0) out[g] = p + fb2[0];
        __syncthreads();
    }
}

// ---------------- host ----------------
extern "C" void kernel_launch(void* const* d_in, const int* in_sizes, int n_in,
                              void* d_out, int out_size, void* d_ws, size_t ws_size,
                              hipStream_t stream)
{
    const float* x     = (const float*)d_in[0];
    const int*   ei    = (const int*)d_in[1];
    const int*   batch = (const int*)d_in[2];
    const float* W1  = (const float*)d_in[3];
    const float* as1 = (const float*)d_in[4];
    const float* ad1 = (const float*)d_in[5];
    const float* g1  = (const float*)d_in[7];
    const float* be1 = (const float*)d_in[8];
    const float* W2  = (const float*)d_in[9];
    const float* as2 = (const float*)d_in[10];
    const float* ad2 = (const float*)d_in[11];
    const float* g2  = (const float*)d_in[13];
    const float* be2 = (const float*)d_in[14];
    const float* W3  = (const float*)d_in[15];
    const float* as3 = (const float*)d_in[16];
    const float* ad3 = (const float*)d_in[17];
    const float* g3  = (const float*)d_in[19];
    const float* be3 = (const float*)d_in[20];
    const float* fw1 = (const float*)d_in[21];
    const float* fb1 = (const float*)d_in[22];
    const float* fw2 = (const float*)d_in[23];
    const float* fb2 = (const float*)d_in[24];
    float* out = (float*)d_out;

    // ---- ws layout ----
    ushort* Hb  = (ushort*)d_ws;                       // [N][128] bf16 GEMM output
    ushort* Bh  = Hb  + (size_t)N_NODES * HID;         // [N][128] bf16 aggregated
    ushort* Wt1 = Bh  + (size_t)N_NODES * HID + 128 * 128;  // pad: gemm stages OOB rows
    ushort* Wt2 = Wt1 + 128 * 32;                      // [128][128]
    ushort* Wt3 = Wt2 + 128 * 128;
    float* als    = (float*)(Wt3 + 128 * 128);
    float* ald    = als + (size_t)N_NODES * 4;
    float* sums1  = ald + (size_t)N_NODES * 4;         // 3 x [NSLICE][256]
    float* sums2  = sums1 + NSLICE * 256;
    float* sums3  = sums2 + NSLICE * 256;
    float* pooled = sums3 + NSLICE * 256;
    float* cnt    = pooled + (size_t)NGRAPH * HID;     // pooled+cnt contiguous
    int*   rowptr = (int*)(cnt + NGRAPH);
    int*   counts = rowptr + (N_NODES + 1);
    int*   cursor = counts + N_NODES;
    int*   bsum   = cursor + N_NODES;
    int*   psrc   = bsum + 512;

    auto cdiv = [](int a, int b) { return (a + b - 1) / b; };

    // ---- fused setup (weight converts + zero-inits, one dispatch) ----
    setup_kernel<<<cdiv(SETUP_TOT, 256), 256, 0, stream>>>(
        W1, W2, W3, Wt1, Wt2, Wt3, sums1, counts, pooled);

    // ---- CSR build (once) ----
    hist_kernel<<<cdiv(N_ETOT, 256), 256, 0, stream>>>(ei, counts);
    scanA_kernel<<<NBLK_SCAN, 256, 0, stream>>>(counts, rowptr, bsum);
    scanC_kernel<<<NBLK_SCAN, 256, 0, stream>>>(rowptr, bsum, cursor);
    scatter_kernel<<<cdiv(N_ETOT, 256), 256, 0, stream>>>(ei, cursor, psrc);

    const int ggrid = cdiv(N_NODES, 128);
    const int agrid = N_NODES / 8;   // 12500, exact (8 nodes per block, 2 per wave)

    // ---- layer 1: K=32 (padded), stage directly from f32 x, 4 heads ----
    mfma_gemm_kernel<32, false, 4, true><<<ggrid, 256, 0, stream>>>(
        nullptr, x, Wt1, nullptr, nullptr, nullptr, as1, ad1, Hb, als, ald, N_NODES);
    agg_kernel<4><<<agrid, 256, 0, stream>>>(Hb, als, ald, rowptr, psrc, Bh);
    bn_stats_kernel<<<STATS_BLOCKS, 256, 0, stream>>>(Bh, sums1);

    // ---- layer 2: K=128, BN(sums1,g1,be1) folded into staging, 4 heads ----
    mfma_gemm_kernel<128, true, 4, false><<<ggrid, 256, 0, stream>>>(
        Bh, nullptr, Wt2, sums1, g1, be1, as2, ad2, Hb, als, ald, N_NODES);
    agg_kernel<4><<<agrid, 256, 0, stream>>>(Hb, als, ald, rowptr, psrc, Bh);
    bn_stats_kernel<<<STATS_BLOCKS, 256, 0, stream>>>(Bh, sums2);

    // ---- layer 3: K=128, BN(sums2,g2,be2) folded into staging, 1 head ----
    mfma_gemm_kernel<128, true, 1, false><<<ggrid, 256, 0, stream>>>(
        Bh, nullptr, Wt3, sums2, g2, be2, as3, ad3, Hb, als, ald, N_NODES);
    agg_kernel<1><<<agrid, 256, 0, stream>>>(Hb, als, ald, rowptr, psrc, Bh);
    bn_stats_kernel<<<STATS_BLOCKS, 256, 0, stream>>>(Bh, sums3);

    // ---- BN(sums3,g3,be3)+ReLU fused pool, then MLP ----
    bn_pool_kernel<<<cdiv(N_NODES, PNPB), 128, 0, stream>>>(
        Bh, sums3, g3, be3, batch, pooled, cnt);
    mlp_kernel<<<NGRAPH / 16, 256, 0, stream>>>(pooled, cnt, fw1, fb1, fw2, fb2, out);
}

// Round 9
// 322.031 us; speedup vs baseline: 1.0671x; 1.0545x over previous
//
#include <hip/hip_runtime.h>

#define N_NODES 100000
#define N_EDGES 300000
#define N_ETOT  400000   // E + N self-loops
#define NGRAPH  4096
#define HID     128
#define NBLK_SCAN 391    // cdiv(N_NODES, 256)
#define PNPB    32       // nodes per block in pool
#define STATS_BLOCKS 512
#define NSLICE  16       // BN-stats atomic slices (16KB/layer table, read by consumers)

typedef __attribute__((ext_vector_type(8))) short short8;
typedef __attribute__((ext_vector_type(8))) ushort ushort8;
typedef __attribute__((ext_vector_type(4))) float f32x4;

__device__ __forceinline__ ushort f2bf(float f) {
    union { float f; unsigned u; } x; x.f = f;
    unsigned r = x.u + 0x7FFF + ((x.u >> 16) & 1);   // round-to-nearest-even
    return (ushort)(r >> 16);
}

__device__ __forceinline__ float bf2f(ushort v) {
    union { unsigned u; float f; } t;
    t.u = ((unsigned)v) << 16;
    return t.f;
}

// unpack uint holding 2 bf16 (channels 2k, 2k+1) -> float2
__device__ __forceinline__ float2 bf2f2(unsigned v) {
    union { unsigned u; float f; } lo, hi;
    lo.u = v << 16;
    hi.u = v & 0xFFFF0000u;
    return make_float2(lo.f, hi.f);
}

// ---------------- fused setup: weight converts + all zero-inits ----------------
#define SETUP_W      36864                       // Wt2 (16384) + Wt3 (16384) + Wt1 (4096)
#define SETUP_SUMS   (SETUP_W + 3 * NSLICE * 256)
#define SETUP_CNTS   (SETUP_SUMS + N_NODES)
#define SETUP_TOT    (SETUP_CNTS + NGRAPH * HID + NGRAPH)
__global__ __launch_bounds__(256) void setup_kernel(
    const float* __restrict__ W1, const float* __restrict__ W2, const float* __restrict__ W3,
    ushort* __restrict__ Wt1, ushort* __restrict__ Wt2, ushort* __restrict__ Wt3,
    float* __restrict__ sums_base, int* __restrict__ counts,
    float* __restrict__ pooled)
{
    const int i = blockIdx.x * 256 + threadIdx.x;
    if (i < 16384) {
        int c = i >> 7, k = i & 127;
        Wt2[c * 128 + k] = f2bf(W2[k * 128 + c]);
    } else if (i < 32768) {
        int j = i - 16384; int c = j >> 7, k = j & 127;
        Wt3[c * 128 + k] = f2bf(W3[k * 128 + c]);
    } else if (i < SETUP_W) {
        int j = i - 32768; int c = j >> 5, k = j & 31;
        Wt1[c * 32 + k] = (k < 22) ? f2bf(W1[k * 128 + c]) : (ushort)0;
    } else if (i < SETUP_SUMS) {
        sums_base[i - SETUP_W] = 0.f;
    } else if (i < SETUP_CNTS) {
        counts[i - SETUP_SUMS] = 0;
    } else if (i < SETUP_TOT) {
        pooled[i - SETUP_CNTS] = 0.f;
    }
}

// ---------------- MFMA GEMM: Cb[M,128](bf16) = act(A)[M,K]@W + fused scores ----------
// 64-row blocks (grid 2x), each wave owns a 16x128 strip:
//  - W staged once into XOR-swizzled Bsm (32KB, ONE barrier); all waves share it.
//  - A-fragments loaded DIRECT global->regs, issued BEFORE the barrier (latency
//    hidden under W staging). No A LDS, no whole-tile staging drain.
//  - Per-wave MFMA loop (KT x 8 tiles), then score epilogue fully in-register
//    (a quad's 16 lanes hold one row's 128 cols -> shfl butterfly, no LDS, no barrier).
// VGPR ~110, LDS 33KB -> 3-4 blocks/CU (r7/r8 were latency-bound at 15% occupancy).
// All fragment values, MFMA order, and score partial-sum order replicate the old
// kernel exactly -> bitwise-identical outputs.
// PRE_BN: scale/shift from raw BN slice table (finalize folded), applied in-reg.
// DX=true: A fragments read from f32 x [N,22] with pad/clamp.
template<int K, bool PRE_BN, int HH, bool DX>
__global__ __launch_bounds__(256) void mfma_gemm_kernel(
    const ushort* __restrict__ Ab, const float* __restrict__ Af,
    const ushort* __restrict__ Wt,
    const float* __restrict__ sums, const float* __restrict__ g, const float* __restrict__ be,
    const float* __restrict__ avs, const float* __restrict__ avd,
    ushort* __restrict__ Cb, float* __restrict__ als, float* __restrict__ ald, int M)
{
    constexpr int SEGS = K / 8;               // 16B segments per W row
    constexpr int SSH  = (K == 128) ? 4 : 2;  // log2(SEGS)
    constexpr int SWM  = SEGS - 1;            // swizzle mask
    constexpr int NPB  = SEGS / 2;            // W staging passes (256 thr, 128 rows)
    constexpr int KT   = K / 32;              // 32-wide k subtiles

    __shared__ ushort Bsm[128 * K];           // K=128: 32 KB; K=32: 8 KB
    __shared__ float scsh[256];               // [0..127]=scale, [128..255]=shift

    const int tid  = threadIdx.x;
    const int wave = tid >> 6;
    const int lane = tid & 63;
    const int ln   = lane & 15;
    const int quad = lane >> 4;
    const int r0   = blockIdx.x * 64 + wave * 16;   // wave's 16-row strip
    const int ra   = r0 + ln;                        // lane's A row

    // ---- issue W staging loads ----
    short8 wR[NPB];
    #pragma unroll
    for (int q = 0; q < NPB; ++q) {
        const int chunk = tid + q * 256;
        const int r   = chunk >> SSH;
        const int seg = chunk & SWM;
        wR[q] = *(const short8*)&Wt[(size_t)r * K + seg * 8];
    }
    // ---- issue A fragment loads (independent of Bsm; hidden under W staging) ----
    short8 aF[KT];
    #pragma unroll
    for (int kt = 0; kt < KT; ++kt) {
        if constexpr (DX) {
            const int rr = min(ra, N_NODES - 1);     // clamp: x has exactly N rows
            #pragma unroll
            for (int i = 0; i < 8; ++i) {
                const int c = kt * 32 + quad * 8 + i;
                const float f = (c < 22) ? Af[(size_t)rr * 22 + c] : 0.f;
                aF[kt][i] = (short)f2bf(f);
            }
        } else {
            aF[kt] = *(const short8*)&Ab[(size_t)ra * K + kt * 32 + quad * 8];
        }
    }
    if constexpr (PRE_BN) {
        // fold bn_finalize: reduce slice table -> scale/shift (while loads in flight)
        if (tid < 128) {
            float s = 0.f, q2 = 0.f;
            for (int b = 0; b < NSLICE; ++b) {
                s  += sums[b * 256 + tid];
                q2 += sums[b * 256 + 128 + tid];
            }
            const float m  = s * (1.f / N_NODES);
            const float v  = q2 * (1.f / N_NODES) - m * m;
            const float sc = g[tid] * rsqrtf(v + 1e-5f);
            scsh[tid]       = sc;
            scsh[tid + 128] = be[tid] - m * sc;
        }
    }
    #pragma unroll
    for (int q = 0; q < NPB; ++q) {
        const int chunk = tid + q * 256;
        const int r   = chunk >> SSH;
        const int seg = chunk & SWM;
        const int sp  = seg ^ (r & SWM);
        *(short8*)&Bsm[r * K + sp * 8] = wR[q];
    }
    __syncthreads();

    if constexpr (PRE_BN) {
        // BN+ReLU+round applied once per A element, in registers (same values as
        // the old staged path: each (row,k) element lives in exactly one fragment)
        #pragma unroll
        for (int kt = 0; kt < KT; ++kt) {
            const int c0 = kt * 32 + quad * 8;
            #pragma unroll
            for (int i = 0; i < 8; ++i) {
                float f = bf2f((ushort)aF[kt][i]);
                f = fmaxf(f * scsh[c0 + i] + scsh[128 + c0 + i], 0.f);
                aF[kt][i] = (short)f2bf(f);
            }
        }
    }

    // ---- MFMA loop: A from regs, B from swizzled LDS (2-way max, free) ----
    f32x4 acc[8] = {};
    #pragma unroll
    for (int kt = 0; kt < KT; ++kt) {
        #pragma unroll
        for (int tc = 0; tc < 8; ++tc) {
            const int ca = tc * 16 + ln;
            const short8 b = *(const short8*)&Bsm[ca * K + (((kt * 4 + quad) ^ (ca & SWM)) * 8)];
            acc[tc] = __builtin_amdgcn_mfma_f32_16x16x32_bf16(aF[kt], b, acc[tc], 0, 0, 0);
        }
    }

    // ---- C write (bf16; C/D layout: col=lane&15, row=quad*4+reg) ----
    #pragma unroll
    for (int rg = 0; rg < 4; ++rg) {
        const int gr = r0 + quad * 4 + rg;
        if (gr < M) {
            #pragma unroll
            for (int tc = 0; tc < 8; ++tc)
                Cb[(size_t)gr * HID + tc * 16 + ln] = f2bf(acc[tc][rg]);
        }
    }

    // ---- fused attention scores: fully in-register (quad's lanes = one row) ----
    float avsr[8], avdr[8];
    #pragma unroll
    for (int tc = 0; tc < 8; ++tc) {
        avsr[tc] = avs[tc * 16 + ln];
        avdr[tc] = avd[tc * 16 + ln];
    }
    #pragma unroll
    for (int rg = 0; rg < 4; ++rg) {
        const int gr = r0 + quad * 4 + rg;
        float s[4], d[4];
        #pragma unroll
        for (int h = 0; h < 4; ++h) {
            float sv = 0.f, dv = 0.f;
            sv += acc[2 * h][rg] * avsr[2 * h];          // same += order as old sA
            sv += acc[2 * h + 1][rg] * avsr[2 * h + 1];
            dv += acc[2 * h][rg] * avdr[2 * h];
            dv += acc[2 * h + 1][rg] * avdr[2 * h + 1];
            s[h] = sv; d[h] = dv;
        }
        #pragma unroll
        for (int m = 1; m < 16; m <<= 1) {
            #pragma unroll
            for (int h = 0; h < 4; ++h) {
                s[h] += __shfl_xor(s[h], m);
                d[h] += __shfl_xor(d[h], m);
            }
        }
        if (ln == 0 && gr < M) {
            if (HH == 4) {
                #pragma unroll
                for (int h = 0; h < 4; ++h) {
                    als[gr * 4 + h] = s[h];
                    ald[gr * 4 + h] = d[h];
                }
            } else {
                als[gr] = ((s[0] + s[1]) + s[2]) + s[3];   // same chunk-sum order as old
                ald[gr] = ((d[0] + d[1]) + d[2]) + d[3];
            }
        }
    }
}

// ---------------- CSR build ----------------
__global__ void hist_kernel(const int* __restrict__ ei, int* __restrict__ counts) {
    int e = blockIdx.x * blockDim.x + threadIdx.x;
    if (e >= N_ETOT) return;
    int dst = (e < N_EDGES) ? ei[N_EDGES + e] : e - N_EDGES;
    atomicAdd(&counts[dst], 1);
}

__global__ __launch_bounds__(256) void scanA_kernel(
    const int* __restrict__ counts, int* __restrict__ rowptr, int* __restrict__ bsum)
{
    __shared__ int ls[256];
    const int t = threadIdx.x;
    const int i = blockIdx.x * 256 + t;
    const int v = (i < N_NODES) ? counts[i] : 0;
    ls[t] = v; __syncthreads();
    #pragma unroll
    for (int off = 1; off < 256; off <<= 1) {
        int add = (t >= off) ? ls[t - off] : 0;
        __syncthreads();
        ls[t] += add;
        __syncthreads();
    }
    if (i < N_NODES) rowptr[i] = ls[t] - v;
    if (t == 255) bsum[blockIdx.x] = ls[255];
}

// scanB folded in: each block redundantly sums bsum[0..bid-1] (1.5 KB, trivial)
__global__ __launch_bounds__(256) void scanC_kernel(
    int* __restrict__ rowptr, const int* __restrict__ bsum, int* __restrict__ cursor)
{
    __shared__ int red[256];
    const int t = threadIdx.x;
    int s = 0;
    for (int b = t; b < (int)blockIdx.x; b += 256) s += bsum[b];
    red[t] = s;
    __syncthreads();
    #pragma unroll
    for (int off = 128; off; off >>= 1) {
        if (t < off) red[t] += red[t + off];
        __syncthreads();
    }
    const int base = red[0];
    const int i = blockIdx.x * 256 + t;
    if (i < N_NODES) {
        const int v = rowptr[i] + base;
        rowptr[i] = v;
        cursor[i] = v;
    }
    if (i == 0) rowptr[N_NODES] = N_ETOT;
}

__global__ void scatter_kernel(const int* __restrict__ ei, int* __restrict__ cursor,
                               int* __restrict__ psrc)
{
    int e = blockIdx.x * blockDim.x + threadIdx.x;
    if (e >= N_ETOT) return;
    int src, dst;
    if (e < N_EDGES) { src = ei[e]; dst = ei[N_EDGES + e]; }
    else             { src = dst = e - N_EDGES; }
    int pos = atomicAdd(&cursor[dst], 1);
    psrc[pos] = src;
}

// ------- single-pass softmax aggregation: 2 nodes per wave (2x memory-level par.) ----
// Pure, no LDS, no barriers. Branchless loads (clamped to r1-1, valid: every node has
// a self-loop) with inactive-edge contributions multiplied to exactly 0.f -> per-node
// accumulation order and butterfly identical to the 1-node/wave version (bitwise same).
template<int HH>
__global__ __launch_bounds__(256) void agg_kernel(
    const ushort* __restrict__ H, const float* __restrict__ als,
    const float* __restrict__ ald, const int* __restrict__ rowptr,
    const int* __restrict__ psrc, ushort* __restrict__ Outb)
{
    const int tid   = threadIdx.x;
    const int w     = tid >> 6;
    const int lane  = tid & 63;
    const int grp   = lane >> 4;       // edge slot 0..3
    const int cl    = lane & 15;       // channels 8*cl .. 8*cl+7
    const int hd    = (HH == 4) ? (cl >> 2) : 0;
    const int nodeA = blockIdx.x * 8 + w * 2;   // grid exact: 12500*8 = N_NODES
    const int nodeB = nodeA + 1;

    const int r0A = rowptr[nodeA];
    const int r1A = rowptr[nodeA + 1];          // == r0B
    const int r1B = rowptr[nodeB + 1];
    const float aldA = (HH == 4) ? ald[nodeA * 4 + hd] : ald[nodeA];
    const float aldB = (HH == 4) ? ald[nodeB * 4 + hd] : ald[nodeB];

    float denA = 0.f, denB = 0.f;
    float accA[8] = {}, accB[8] = {};
    int pA = r0A + grp;
    int pB = r1A + grp;
    while (pA < r1A || pB < r1B) {
        const bool aA = pA < r1A;
        const bool aB = pB < r1B;
        const int qA = aA ? pA : (r1A - 1);     // always-valid clamp (self-loop => deg>=1)
        const int qB = aB ? pB : (r1B - 1);
        const int sA = psrc[qA];
        const int sB = psrc[qB];
        const float svA = (HH == 4) ? als[sA * 4 + hd] : als[sA];
        const float svB = (HH == 4) ? als[sB * 4 + hd] : als[sB];
        const uint4 hvA = *(const uint4*)&H[(size_t)sA * HID + cl * 8];
        const uint4 hvB = *(const uint4*)&H[(size_t)sB * HID + cl * 8];

        float vA = svA + aldA; vA = (vA > 0.f) ? vA : 0.2f * vA;
        float vB = svB + aldB; vB = (vB > 0.f) ? vB : 0.2f * vB;
        const float exA = aA ? __expf(vA) : 0.f;
        const float exB = aB ? __expf(vB) : 0.f;
        {
            const float2 h0 = bf2f2(hvA.x), h1 = bf2f2(hvA.y);
            const float2 h2 = bf2f2(hvA.z), h3 = bf2f2(hvA.w);
            accA[0] += exA * h0.x; accA[1] += exA * h0.y;
            accA[2] += exA * h1.x; accA[3] += exA * h1.y;
            accA[4] += exA * h2.x; accA[5] += exA * h2.y;
            accA[6] += exA * h3.x; accA[7] += exA * h3.y;
            denA += exA;
        }
        {
            const float2 h0 = bf2f2(hvB.x), h1 = bf2f2(hvB.y);
            const float2 h2 = bf2f2(hvB.z), h3 = bf2f2(hvB.w);
            accB[0] += exB * h0.x; accB[1] += exB * h0.y;
            accB[2] += exB * h1.x; accB[3] += exB * h1.y;
            accB[4] += exB * h2.x; accB[5] += exB * h2.y;
            accB[6] += exB * h3.x; accB[7] += exB * h3.y;
            denB += exB;
        }
        pA += 4; pB += 4;
    }
    #pragma unroll
    for (int m = 16; m < 64; m <<= 1) {
        denA += __shfl_xor(denA, m);
        denB += __shfl_xor(denB, m);
        #pragma unroll
        for (int i = 0; i < 8; ++i) {
            accA[i] += __shfl_xor(accA[i], m);
            accB[i] += __shfl_xor(accB[i], m);
        }
    }
    if (grp == 0) {
        const float inv = 1.f / (denA + 1e-16f);
        ushort8 o;
        #pragma unroll
        for (int i = 0; i < 8; ++i) o[i] = f2bf(accA[i] * inv);
        *(ushort8*)&Outb[(size_t)nodeA * HID + cl * 8] = o;
    } else if (grp == 1) {
        const float inv = 1.f / (denB + 1e-16f);
        ushort8 o;
        #pragma unroll
        for (int i = 0; i < 8; ++i) o[i] = f2bf(accB[i] * inv);
        *(ushort8*)&Outb[(size_t)nodeB * HID + cl * 8] = o;
    }
}

// ---------------- BN stats: vectorized 16B loads, register accum, sliced atomics ----
__global__ __launch_bounds__(256) void bn_stats_kernel(
    const ushort* __restrict__ X, float* __restrict__ sums_sl)
{
    __shared__ float ls[16][128], lq[16][128];   // 16 KB
    const int tid = threadIdx.x;
    const int ro  = tid >> 4;         // row slice 0..15
    const int ci  = tid & 15;         // chunk of 8 channels
    const int c0  = ci * 8;
    const int rpb = (N_NODES + STATS_BLOCKS - 1) / STATS_BLOCKS;   // 196
    const int r0  = blockIdx.x * rpb;
    const int r1  = min(r0 + rpb, N_NODES);

    float s[8] = {}, q[8] = {};
    for (int r = r0 + ro; r < r1; r += 16) {
        const ushort8 v = *(const ushort8*)&X[(size_t)r * HID + c0];
        #pragma unroll
        for (int j = 0; j < 8; ++j) {
            const float f = bf2f(v[j]);
            s[j] += f; q[j] += f * f;
        }
    }
    #pragma unroll
    for (int j = 0; j < 8; ++j) { ls[ro][c0 + j] = s[j]; lq[ro][c0 + j] = q[j]; }
    __syncthreads();
    const int half = tid >> 7;
    const int c    = tid & 127;
    float acc = 0.f;
    if (half == 0) {
        #pragma unroll
        for (int k = 0; k < 16; ++k) acc += ls[k][c];
    } else {
        #pragma unroll
        for (int k = 0; k < 16; ++k) acc += lq[k][c];
    }
    atomicAdd(&sums_sl[(blockIdx.x & (NSLICE - 1)) * 256 + tid], acc);
}

// ---------------- layer-3 BN+ReLU fused pool (finalize folded; batch sorted) --------
__global__ __launch_bounds__(128) void bn_pool_kernel(
    const ushort* __restrict__ X,
    const float* __restrict__ sums, const float* __restrict__ g, const float* __restrict__ be,
    const int* __restrict__ batch, float* __restrict__ pooled, float* __restrict__ cnt)
{
    const int c = threadIdx.x;
    // fold bn_finalize: per-thread channel scale/shift from raw slice table
    float s = 0.f, q2 = 0.f;
    for (int b = 0; b < NSLICE; ++b) {
        s  += sums[b * 256 + c];
        q2 += sums[b * 256 + 128 + c];
    }
    const float m  = s * (1.f / N_NODES);
    const float vv = q2 * (1.f / N_NODES) - m * m;
    const float sc = g[c] * rsqrtf(vv + 1e-5f);
    const float sh = be[c] - m * sc;

    const int n0 = blockIdx.x * PNPB;
    const int n1 = min(n0 + PNPB, N_NODES);
    int gcur = batch[n0];
    float acc = 0.f;
    int run = 0;
    for (int n = n0; n < n1; ++n) {
        const int gg = batch[n];
        if (gg != gcur) {
            atomicAdd(&pooled[(size_t)gcur * HID + c], acc);
            if (c == 0) atomicAdd(&cnt[gcur], (float)run);
            acc = 0.f; run = 0; gcur = gg;
        }
        const float v = bf2f(X[(size_t)n * HID + c]) * sc + sh;
        acc += fmaxf(v, 0.f);
        ++run;
    }
    atomicAdd(&pooled[(size_t)gcur * HID + c], acc);
    if (c == 0) atomicAdd(&cnt[gcur], (float)run);
}

// ---------------- MLP head ----------------
__global__ __launch_bounds__(256) void mlp_kernel(
    const float* __restrict__ pooled, const float* __restrict__ cnt,
    const float* __restrict__ fw1, const float* __restrict__ fb1,
    const float* __restrict__ fw2, const float* __restrict__ fb2,
    float* __restrict__ out)
{
    __shared__ float w1[HID * 64];
    __shared__ float rows[4][HID];
    const int tid = threadIdx.x;
    for (int i = tid; i < HID * 64; i += 256) w1[i] = fw1[i];
    const int gl = tid >> 6;
    const int j  = tid & 63;
    const float b1 = fb1[j];
    const float w2 = fw2[j];
    __syncthreads();
    #pragma unroll
    for (int it = 0; it < 4; ++it) {
        const int g = blockIdx.x * 16 + it * 4 + gl;
        const float inv = 1.f / fmaxf(cnt[g], 1.f);
        rows[gl][j]      = pooled[(size_t)g * HID + j] * inv;
        rows[gl][j + 64] = pooled[(size_t)g * HID + 64 + j] * inv;
        __syncthreads();
        float z = b1;
        #pragma unroll 8
        for (int c2 = 0; c2 < HID; ++c2) z += rows[gl][c2] * w1[c2 * 64 + j];
        z = fmaxf(z, 0.f);
        float p = z * w2;
        #pragma unroll
        for (int off = 32; off; off >>= 1) p += __shfl_down(p, off);
        if (j == 0) out[g] = p + fb2[0];
        __syncthreads();
    }
}

// ---------------- host ----------------
extern "C" void kernel_launch(void* const* d_in, const int* in_sizes, int n_in,
                              void* d_out, int out_size, void* d_ws, size_t ws_size,
                              hipStream_t stream)
{
    const float* x     = (const float*)d_in[0];
    const int*   ei    = (const int*)d_in[1];
    const int*   batch = (const int*)d_in[2];
    const float* W1  = (const float*)d_in[3];
    const float* as1 = (const float*)d_in[4];
    const float* ad1 = (const float*)d_in[5];
    const float* g1  = (const float*)d_in[7];
    const float* be1 = (const float*)d_in[8];
    const float* W2  = (const float*)d_in[9];
    const float* as2 = (const float*)d_in[10];
    const float* ad2 = (const float*)d_in[11];
    const float* g2  = (const float*)d_in[13];
    const float* be2 = (const float*)d_in[14];
    const float* W3  = (const float*)d_in[15];
    const float* as3 = (const float*)d_in[16];
    const float* ad3 = (const float*)d_in[17];
    const float* g3  = (const float*)d_in[19];
    const float* be3 = (const float*)d_in[20];
    const float* fw1 = (const float*)d_in[21];
    const float* fb1 = (const float*)d_in[22];
    const float* fw2 = (const float*)d_in[23];
    const float* fb2 = (const float*)d_in[24];
    float* out = (float*)d_out;

    // ---- ws layout ----
    ushort* Hb  = (ushort*)d_ws;                       // [N][128] bf16 GEMM output
    ushort* Bh  = Hb  + (size_t)N_NODES * HID;         // [N][128] bf16 aggregated
    ushort* Wt1 = Bh  + (size_t)N_NODES * HID + 128 * 128;  // pad: gemm reads OOB rows
    ushort* Wt2 = Wt1 + 128 * 32;                      // [128][128]
    ushort* Wt3 = Wt2 + 128 * 128;
    float* als    = (float*)(Wt3 + 128 * 128);
    float* ald    = als + (size_t)N_NODES * 4;
    float* sums1  = ald + (size_t)N_NODES * 4;         // 3 x [NSLICE][256]
    float* sums2  = sums1 + NSLICE * 256;
    float* sums3  = sums2 + NSLICE * 256;
    float* pooled = sums3 + NSLICE * 256;
    float* cnt    = pooled + (size_t)NGRAPH * HID;     // pooled+cnt contiguous
    int*   rowptr = (int*)(cnt + NGRAPH);
    int*   counts = rowptr + (N_NODES + 1);
    int*   cursor = counts + N_NODES;
    int*   bsum   = cursor + N_NODES;
    int*   psrc   = bsum + 512;

    auto cdiv = [](int a, int b) { return (a + b - 1) / b; };

    // ---- fused setup (weight converts + zero-inits, one dispatch) ----
    setup_kernel<<<cdiv(SETUP_TOT, 256), 256, 0, stream>>>(
        W1, W2, W3, Wt1, Wt2, Wt3, sums1, counts, pooled);

    // ---- CSR build (once) ----
    hist_kernel<<<cdiv(N_ETOT, 256), 256, 0, stream>>>(ei, counts);
    scanA_kernel<<<NBLK_SCAN, 256, 0, stream>>>(counts, rowptr, bsum);
    scanC_kernel<<<NBLK_SCAN, 256, 0, stream>>>(rowptr, bsum, cursor);
    scatter_kernel<<<cdiv(N_ETOT, 256), 256, 0, stream>>>(ei, cursor, psrc);

    const int ggrid = cdiv(N_NODES, 64);   // 1563 blocks (64 rows/block, 16/wave)
    const int agrid = N_NODES / 8;   // 12500, exact (8 nodes per block, 2 per wave)

    // ---- layer 1: K=32 (padded), A direct from f32 x, 4 heads ----
    mfma_gemm_kernel<32, false, 4, true><<<ggrid, 256, 0, stream>>>(
        nullptr, x, Wt1, nullptr, nullptr, nullptr, as1, ad1, Hb, als, ald, N_NODES);
    agg_kernel<4><<<agrid, 256, 0, stream>>>(Hb, als, ald, rowptr, psrc, Bh);
    bn_stats_kernel<<<STATS_BLOCKS, 256, 0, stream>>>(Bh, sums1);

    // ---- layer 2: K=128, BN(sums1,g1,be1) folded, 4 heads ----
    mfma_gemm_kernel<128, true, 4, false><<<ggrid, 256, 0, stream>>>(
        Bh, nullptr, Wt2, sums1, g1, be1, as2, ad2, Hb, als, ald, N_NODES);
    agg_kernel<4><<<agrid, 256, 0, stream>>>(Hb, als, ald, rowptr, psrc, Bh);
    bn_stats_kernel<<<STATS_BLOCKS, 256, 0, stream>>>(Bh, sums2);

    // ---- layer 3: K=128, BN(sums2,g2,be2) folded, 1 head ----
    mfma_gemm_kernel<128, true, 1, false><<<ggrid, 256, 0, stream>>>(
        Bh, nullptr, Wt3, sums2, g2, be2, as3, ad3, Hb, als, ald, N_NODES);
    agg_kernel<1><<<agrid, 256, 0, stream>>>(Hb, als, ald, rowptr, psrc, Bh);
    bn_stats_kernel<<<STATS_BLOCKS, 256, 0, stream>>>(Bh, sums3);

    // ---- BN(sums3,g3,be3)+ReLU fused pool, then MLP ----
    bn_pool_kernel<<<cdiv(N_NODES, PNPB), 128, 0, stream>>>(
        Bh, sums3, g3, be3, batch, pooled, cnt);
    mlp_kernel<<<NGRAPH / 16, 256, 0, stream>>>(pooled, cnt, fw1, fb1, fw2, fb2, out);
}

// Round 10
// 318.215 us; speedup vs baseline: 1.0799x; 1.0120x over previous
//
#include <hip/hip_runtime.h>

#define N_NODES 100000
#define N_EDGES 300000
#define N_ETOT  400000   // E + N self-loops
#define NGRAPH  4096
#define HID     128
#define NBLK_SCAN 391    // cdiv(N_NODES, 256)
#define PNPB    32       // nodes per block in pool
#define STATS_BLOCKS 512
#define NSLICE  16       // BN-stats atomic slices (16KB/layer table, read by consumers)

typedef __attribute__((ext_vector_type(8))) short short8;
typedef __attribute__((ext_vector_type(8))) ushort ushort8;
typedef __attribute__((ext_vector_type(4))) float f32x4;

__device__ __forceinline__ ushort f2bf(float f) {
    union { float f; unsigned u; } x; x.f = f;
    unsigned r = x.u + 0x7FFF + ((x.u >> 16) & 1);   // round-to-nearest-even
    return (ushort)(r >> 16);
}

__device__ __forceinline__ float bf2f(ushort v) {
    union { unsigned u; float f; } t;
    t.u = ((unsigned)v) << 16;
    return t.f;
}

// unpack uint holding 2 bf16 (channels 2k, 2k+1) -> float2
__device__ __forceinline__ float2 bf2f2(unsigned v) {
    union { unsigned u; float f; } lo, hi;
    lo.u = v << 16;
    hi.u = v & 0xFFFF0000u;
    return make_float2(lo.f, hi.f);
}

// ---------------- fused setup: weight converts + all zero-inits ----------------
#define SETUP_W      36864                       // Wt2 (16384) + Wt3 (16384) + Wt1 (4096)
#define SETUP_SUMS   (SETUP_W + 3 * NSLICE * 256)
#define SETUP_CNTS   (SETUP_SUMS + N_NODES)
#define SETUP_TOT    (SETUP_CNTS + NGRAPH * HID + NGRAPH)
__global__ __launch_bounds__(256) void setup_kernel(
    const float* __restrict__ W1, const float* __restrict__ W2, const float* __restrict__ W3,
    ushort* __restrict__ Wt1, ushort* __restrict__ Wt2, ushort* __restrict__ Wt3,
    float* __restrict__ sums_base, int* __restrict__ counts,
    float* __restrict__ pooled)
{
    const int i = blockIdx.x * 256 + threadIdx.x;
    if (i < 16384) {
        int c = i >> 7, k = i & 127;
        Wt2[c * 128 + k] = f2bf(W2[k * 128 + c]);
    } else if (i < 32768) {
        int j = i - 16384; int c = j >> 7, k = j & 127;
        Wt3[c * 128 + k] = f2bf(W3[k * 128 + c]);
    } else if (i < SETUP_W) {
        int j = i - 32768; int c = j >> 5, k = j & 31;
        Wt1[c * 32 + k] = (k < 22) ? f2bf(W1[k * 128 + c]) : (ushort)0;
    } else if (i < SETUP_SUMS) {
        sums_base[i - SETUP_W] = 0.f;
    } else if (i < SETUP_CNTS) {
        counts[i - SETUP_SUMS] = 0;
    } else if (i < SETUP_TOT) {
        pooled[i - SETUP_CNTS] = 0.f;
    }
}

// ---------------- MFMA GEMM: Cb[M,128](bf16) = act(A)[M,K]@W + fused scores ----------
// 64-row blocks, each wave owns a 16x128 strip:
//  - W staged once into XOR-swizzled Bsm (32KB, ONE barrier); all waves share it.
//  - A-fragments loaded DIRECT global->regs, issued BEFORE the barrier.
//  - Per-wave MFMA loop (KT x 8 tiles), score epilogue fully in-register.
// PRE_BN: scale/shift from raw BN slice table (finalize folded), applied in-reg.
// DX=true: A fragments read from f32 x [N,22] with pad/clamp.
template<int K, bool PRE_BN, int HH, bool DX>
__global__ __launch_bounds__(256) void mfma_gemm_kernel(
    const ushort* __restrict__ Ab, const float* __restrict__ Af,
    const ushort* __restrict__ Wt,
    const float* __restrict__ sums, const float* __restrict__ g, const float* __restrict__ be,
    const float* __restrict__ avs, const float* __restrict__ avd,
    ushort* __restrict__ Cb, float* __restrict__ als, float* __restrict__ ald, int M)
{
    constexpr int SEGS = K / 8;               // 16B segments per W row
    constexpr int SSH  = (K == 128) ? 4 : 2;  // log2(SEGS)
    constexpr int SWM  = SEGS - 1;            // swizzle mask
    constexpr int NPB  = SEGS / 2;            // W staging passes (256 thr, 128 rows)
    constexpr int KT   = K / 32;              // 32-wide k subtiles

    __shared__ ushort Bsm[128 * K];           // K=128: 32 KB; K=32: 8 KB
    __shared__ float scsh[256];               // [0..127]=scale, [128..255]=shift

    const int tid  = threadIdx.x;
    const int wave = tid >> 6;
    const int lane = tid & 63;
    const int ln   = lane & 15;
    const int quad = lane >> 4;
    const int r0   = blockIdx.x * 64 + wave * 16;   // wave's 16-row strip
    const int ra   = r0 + ln;                        // lane's A row

    // ---- issue W staging loads ----
    short8 wR[NPB];
    #pragma unroll
    for (int q = 0; q < NPB; ++q) {
        const int chunk = tid + q * 256;
        const int r   = chunk >> SSH;
        const int seg = chunk & SWM;
        wR[q] = *(const short8*)&Wt[(size_t)r * K + seg * 8];
    }
    // ---- issue A fragment loads (independent of Bsm; hidden under W staging) ----
    short8 aF[KT];
    #pragma unroll
    for (int kt = 0; kt < KT; ++kt) {
        if constexpr (DX) {
            const int rr = min(ra, N_NODES - 1);     // clamp: x has exactly N rows
            #pragma unroll
            for (int i = 0; i < 8; ++i) {
                const int c = kt * 32 + quad * 8 + i;
                const float f = (c < 22) ? Af[(size_t)rr * 22 + c] : 0.f;
                aF[kt][i] = (short)f2bf(f);
            }
        } else {
            aF[kt] = *(const short8*)&Ab[(size_t)ra * K + kt * 32 + quad * 8];
        }
    }
    if constexpr (PRE_BN) {
        // fold bn_finalize: reduce slice table -> scale/shift (while loads in flight)
        if (tid < 128) {
            float s = 0.f, q2 = 0.f;
            for (int b = 0; b < NSLICE; ++b) {
                s  += sums[b * 256 + tid];
                q2 += sums[b * 256 + 128 + tid];
            }
            const float m  = s * (1.f / N_NODES);
            const float v  = q2 * (1.f / N_NODES) - m * m;
            const float sc = g[tid] * rsqrtf(v + 1e-5f);
            scsh[tid]       = sc;
            scsh[tid + 128] = be[tid] - m * sc;
        }
    }
    #pragma unroll
    for (int q = 0; q < NPB; ++q) {
        const int chunk = tid + q * 256;
        const int r   = chunk >> SSH;
        const int seg = chunk & SWM;
        const int sp  = seg ^ (r & SWM);
        *(short8*)&Bsm[r * K + sp * 8] = wR[q];
    }
    __syncthreads();

    if constexpr (PRE_BN) {
        // BN+ReLU+round applied once per A element, in registers (same values as
        // the old staged path: each (row,k) element lives in exactly one fragment)
        #pragma unroll
        for (int kt = 0; kt < KT; ++kt) {
            const int c0 = kt * 32 + quad * 8;
            #pragma unroll
            for (int i = 0; i < 8; ++i) {
                float f = bf2f((ushort)aF[kt][i]);
                f = fmaxf(f * scsh[c0 + i] + scsh[128 + c0 + i], 0.f);
                aF[kt][i] = (short)f2bf(f);
            }
        }
    }

    // ---- MFMA loop: A from regs, B from swizzled LDS (2-way max, free) ----
    f32x4 acc[8] = {};
    #pragma unroll
    for (int kt = 0; kt < KT; ++kt) {
        #pragma unroll
        for (int tc = 0; tc < 8; ++tc) {
            const int ca = tc * 16 + ln;
            const short8 b = *(const short8*)&Bsm[ca * K + (((kt * 4 + quad) ^ (ca & SWM)) * 8)];
            acc[tc] = __builtin_amdgcn_mfma_f32_16x16x32_bf16(aF[kt], b, acc[tc], 0, 0, 0);
        }
    }

    // ---- C write (bf16; C/D layout: col=lane&15, row=quad*4+reg) ----
    #pragma unroll
    for (int rg = 0; rg < 4; ++rg) {
        const int gr = r0 + quad * 4 + rg;
        if (gr < M) {
            #pragma unroll
            for (int tc = 0; tc < 8; ++tc)
                Cb[(size_t)gr * HID + tc * 16 + ln] = f2bf(acc[tc][rg]);
        }
    }

    // ---- fused attention scores: fully in-register (quad's lanes = one row) ----
    float avsr[8], avdr[8];
    #pragma unroll
    for (int tc = 0; tc < 8; ++tc) {
        avsr[tc] = avs[tc * 16 + ln];
        avdr[tc] = avd[tc * 16 + ln];
    }
    #pragma unroll
    for (int rg = 0; rg < 4; ++rg) {
        const int gr = r0 + quad * 4 + rg;
        float s[4], d[4];
        #pragma unroll
        for (int h = 0; h < 4; ++h) {
            float sv = 0.f, dv = 0.f;
            sv += acc[2 * h][rg] * avsr[2 * h];          // same += order as old sA
            sv += acc[2 * h + 1][rg] * avsr[2 * h + 1];
            dv += acc[2 * h][rg] * avdr[2 * h];
            dv += acc[2 * h + 1][rg] * avdr[2 * h + 1];
            s[h] = sv; d[h] = dv;
        }
        #pragma unroll
        for (int m = 1; m < 16; m <<= 1) {
            #pragma unroll
            for (int h = 0; h < 4; ++h) {
                s[h] += __shfl_xor(s[h], m);
                d[h] += __shfl_xor(d[h], m);
            }
        }
        if (ln == 0 && gr < M) {
            if (HH == 4) {
                #pragma unroll
                for (int h = 0; h < 4; ++h) {
                    als[gr * 4 + h] = s[h];
                    ald[gr * 4 + h] = d[h];
                }
            } else {
                als[gr] = ((s[0] + s[1]) + s[2]) + s[3];   // same chunk-sum order as old
                ald[gr] = ((d[0] + d[1]) + d[2]) + d[3];
            }
        }
    }
}

// ---------------- CSR build ----------------
__global__ void hist_kernel(const int* __restrict__ ei, int* __restrict__ counts) {
    int e = blockIdx.x * blockDim.x + threadIdx.x;
    if (e >= N_ETOT) return;
    int dst = (e < N_EDGES) ? ei[N_EDGES + e] : e - N_EDGES;
    atomicAdd(&counts[dst], 1);
}

__global__ __launch_bounds__(256) void scanA_kernel(
    const int* __restrict__ counts, int* __restrict__ rowptr, int* __restrict__ bsum)
{
    __shared__ int ls[256];
    const int t = threadIdx.x;
    const int i = blockIdx.x * 256 + t;
    const int v = (i < N_NODES) ? counts[i] : 0;
    ls[t] = v; __syncthreads();
    #pragma unroll
    for (int off = 1; off < 256; off <<= 1) {
        int add = (t >= off) ? ls[t - off] : 0;
        __syncthreads();
        ls[t] += add;
        __syncthreads();
    }
    if (i < N_NODES) rowptr[i] = ls[t] - v;
    if (t == 255) bsum[blockIdx.x] = ls[255];
}

// scanB folded in: each block redundantly sums bsum[0..bid-1] (1.5 KB, trivial)
__global__ __launch_bounds__(256) void scanC_kernel(
    int* __restrict__ rowptr, const int* __restrict__ bsum, int* __restrict__ cursor)
{
    __shared__ int red[256];
    const int t = threadIdx.x;
    int s = 0;
    for (int b = t; b < (int)blockIdx.x; b += 256) s += bsum[b];
    red[t] = s;
    __syncthreads();
    #pragma unroll
    for (int off = 128; off; off >>= 1) {
        if (t < off) red[t] += red[t + off];
        __syncthreads();
    }
    const int base = red[0];
    const int i = blockIdx.x * 256 + t;
    if (i < N_NODES) {
        const int v = rowptr[i] + base;
        rowptr[i] = v;
        cursor[i] = v;
    }
    if (i == 0) rowptr[N_NODES] = N_ETOT;
}

__global__ void scatter_kernel(const int* __restrict__ ei, int* __restrict__ cursor,
                               int* __restrict__ psrc)
{
    int e = blockIdx.x * blockDim.x + threadIdx.x;
    if (e >= N_ETOT) return;
    int src, dst;
    if (e < N_EDGES) { src = ei[e]; dst = ei[N_EDGES + e]; }
    else             { src = dst = e - N_EDGES; }
    int pos = atomicAdd(&cursor[dst], 1);
    psrc[pos] = src;
}

// ------- single-pass softmax aggregation: 2 nodes/wave + psrc chain-break prefetch ---
// Pure, no LDS, no barriers. The psrc[p] -> H[src] two-level dependent gather is
// pipelined: next iteration's psrc is loaded while the current H rows are in flight,
// so each iteration's critical path is one gather level, not two. Arithmetic values,
// order, and gating are IDENTICAL to the r6 version (bitwise same outputs); only
// load scheduling changes. Branchless clamp (valid: every node has a self-loop).
template<int HH>
__global__ __launch_bounds__(256) void agg_kernel(
    const ushort* __restrict__ H, const float* __restrict__ als,
    const float* __restrict__ ald, const int* __restrict__ rowptr,
    const int* __restrict__ psrc, ushort* __restrict__ Outb)
{
    const int tid   = threadIdx.x;
    const int w     = tid >> 6;
    const int lane  = tid & 63;
    const int grp   = lane >> 4;       // edge slot 0..3
    const int cl    = lane & 15;       // channels 8*cl .. 8*cl+7
    const int hd    = (HH == 4) ? (cl >> 2) : 0;
    const int nodeA = blockIdx.x * 8 + w * 2;   // grid exact: 12500*8 = N_NODES
    const int nodeB = nodeA + 1;

    const int r0A = rowptr[nodeA];
    const int r1A = rowptr[nodeA + 1];          // == r0B
    const int r1B = rowptr[nodeB + 1];
    const float aldA = (HH == 4) ? ald[nodeA * 4 + hd] : ald[nodeA];
    const float aldB = (HH == 4) ? ald[nodeB * 4 + hd] : ald[nodeB];

    float denA = 0.f, denB = 0.f;
    float accA[8] = {}, accB[8] = {};
    int pA = r0A + grp;
    int pB = r1A + grp;
    bool aA = pA < r1A;
    bool aB = pB < r1B;
    // prologue: resolve iteration 0's src indices (clamped loads always valid)
    int sA = psrc[aA ? pA : (r1A - 1)];
    int sB = psrc[aB ? pB : (r1B - 1)];
    while (pA < r1A || pB < r1B) {
        // issue current H/als loads immediately (addresses already resolved)
        const float svA = (HH == 4) ? als[sA * 4 + hd] : als[sA];
        const float svB = (HH == 4) ? als[sB * 4 + hd] : als[sB];
        const uint4 hvA = *(const uint4*)&H[(size_t)sA * HID + cl * 8];
        const uint4 hvB = *(const uint4*)&H[(size_t)sB * HID + cl * 8];
        // prefetch NEXT iteration's psrc while H loads are in flight
        const int pA2 = pA + 4, pB2 = pB + 4;
        const bool aA2 = pA2 < r1A;
        const bool aB2 = pB2 < r1B;
        const int sA2 = psrc[aA2 ? pA2 : (r1A - 1)];
        const int sB2 = psrc[aB2 ? pB2 : (r1B - 1)];

        float vA = svA + aldA; vA = (vA > 0.f) ? vA : 0.2f * vA;
        float vB = svB + aldB; vB = (vB > 0.f) ? vB : 0.2f * vB;
        const float exA = aA ? __expf(vA) : 0.f;
        const float exB = aB ? __expf(vB) : 0.f;
        {
            const float2 h0 = bf2f2(hvA.x), h1 = bf2f2(hvA.y);
            const float2 h2 = bf2f2(hvA.z), h3 = bf2f2(hvA.w);
            accA[0] += exA * h0.x; accA[1] += exA * h0.y;
            accA[2] += exA * h1.x; accA[3] += exA * h1.y;
            accA[4] += exA * h2.x; accA[5] += exA * h2.y;
            accA[6] += exA * h3.x; accA[7] += exA * h3.y;
            denA += exA;
        }
        {
            const float2 h0 = bf2f2(hvB.x), h1 = bf2f2(hvB.y);
            const float2 h2 = bf2f2(hvB.z), h3 = bf2f2(hvB.w);
            accB[0] += exB * h0.x; accB[1] += exB * h0.y;
            accB[2] += exB * h1.x; accB[3] += exB * h1.y;
            accB[4] += exB * h2.x; accB[5] += exB * h2.y;
            accB[6] += exB * h3.x; accB[7] += exB * h3.y;
            denB += exB;
        }
        pA = pA2; pB = pB2;
        aA = aA2; aB = aB2;
        sA = sA2; sB = sB2;
    }
    #pragma unroll
    for (int m = 16; m < 64; m <<= 1) {
        denA += __shfl_xor(denA, m);
        denB += __shfl_xor(denB, m);
        #pragma unroll
        for (int i = 0; i < 8; ++i) {
            accA[i] += __shfl_xor(accA[i], m);
            accB[i] += __shfl_xor(accB[i], m);
        }
    }
    if (grp == 0) {
        const float inv = 1.f / (denA + 1e-16f);
        ushort8 o;
        #pragma unroll
        for (int i = 0; i < 8; ++i) o[i] = f2bf(accA[i] * inv);
        *(ushort8*)&Outb[(size_t)nodeA * HID + cl * 8] = o;
    } else if (grp == 1) {
        const float inv = 1.f / (denB + 1e-16f);
        ushort8 o;
        #pragma unroll
        for (int i = 0; i < 8; ++i) o[i] = f2bf(accB[i] * inv);
        *(ushort8*)&Outb[(size_t)nodeB * HID + cl * 8] = o;
    }
}

// ---------------- BN stats: vectorized 16B loads, register accum, sliced atomics ----
__global__ __launch_bounds__(256) void bn_stats_kernel(
    const ushort* __restrict__ X, float* __restrict__ sums_sl)
{
    __shared__ float ls[16][128], lq[16][128];   // 16 KB
    const int tid = threadIdx.x;
    const int ro  = tid >> 4;         // row slice 0..15
    const int ci  = tid & 15;         // chunk of 8 channels
    const int c0  = ci * 8;
    const int rpb = (N_NODES + STATS_BLOCKS - 1) / STATS_BLOCKS;   // 196
    const int r0  = blockIdx.x * rpb;
    const int r1  = min(r0 + rpb, N_NODES);

    float s[8] = {}, q[8] = {};
    for (int r = r0 + ro; r < r1; r += 16) {
        const ushort8 v = *(const ushort8*)&X[(size_t)r * HID + c0];
        #pragma unroll
        for (int j = 0; j < 8; ++j) {
            const float f = bf2f(v[j]);
            s[j] += f; q[j] += f * f;
        }
    }
    #pragma unroll
    for (int j = 0; j < 8; ++j) { ls[ro][c0 + j] = s[j]; lq[ro][c0 + j] = q[j]; }
    __syncthreads();
    const int half = tid >> 7;
    const int c    = tid & 127;
    float acc = 0.f;
    if (half == 0) {
        #pragma unroll
        for (int k = 0; k < 16; ++k) acc += ls[k][c];
    } else {
        #pragma unroll
        for (int k = 0; k < 16; ++k) acc += lq[k][c];
    }
    atomicAdd(&sums_sl[(blockIdx.x & (NSLICE - 1)) * 256 + tid], acc);
}

// ---------------- layer-3 BN+ReLU fused pool (finalize folded; batch sorted) --------
__global__ __launch_bounds__(128) void bn_pool_kernel(
    const ushort* __restrict__ X,
    const float* __restrict__ sums, const float* __restrict__ g, const float* __restrict__ be,
    const int* __restrict__ batch, float* __restrict__ pooled, float* __restrict__ cnt)
{
    const int c = threadIdx.x;
    // fold bn_finalize: per-thread channel scale/shift from raw slice table
    float s = 0.f, q2 = 0.f;
    for (int b = 0; b < NSLICE; ++b) {
        s  += sums[b * 256 + c];
        q2 += sums[b * 256 + 128 + c];
    }
    const float m  = s * (1.f / N_NODES);
    const float vv = q2 * (1.f / N_NODES) - m * m;
    const float sc = g[c] * rsqrtf(vv + 1e-5f);
    const float sh = be[c] - m * sc;

    const int n0 = blockIdx.x * PNPB;
    const int n1 = min(n0 + PNPB, N_NODES);
    int gcur = batch[n0];
    float acc = 0.f;
    int run = 0;
    for (int n = n0; n < n1; ++n) {
        const int gg = batch[n];
        if (gg != gcur) {
            atomicAdd(&pooled[(size_t)gcur * HID + c], acc);
            if (c == 0) atomicAdd(&cnt[gcur], (float)run);
            acc = 0.f; run = 0; gcur = gg;
        }
        const float v = bf2f(X[(size_t)n * HID + c]) * sc + sh;
        acc += fmaxf(v, 0.f);
        ++run;
    }
    atomicAdd(&pooled[(size_t)gcur * HID + c], acc);
    if (c == 0) atomicAdd(&cnt[gcur], (float)run);
}

// ---------------- MLP head ----------------
__global__ __launch_bounds__(256) void mlp_kernel(
    const float* __restrict__ pooled, const float* __restrict__ cnt,
    const float* __restrict__ fw1, const float* __restrict__ fb1,
    const float* __restrict__ fw2, const float* __restrict__ fb2,
    float* __restrict__ out)
{
    __shared__ float w1[HID * 64];
    __shared__ float rows[4][HID];
    const int tid = threadIdx.x;
    for (int i = tid; i < HID * 64; i += 256) w1[i] = fw1[i];
    const int gl = tid >> 6;
    const int j  = tid & 63;
    const float b1 = fb1[j];
    const float w2 = fw2[j];
    __syncthreads();
    #pragma unroll
    for (int it = 0; it < 4; ++it) {
        const int g = blockIdx.x * 16 + it * 4 + gl;
        const float inv = 1.f / fmaxf(cnt[g], 1.f);
        rows[gl][j]      = pooled[(size_t)g * HID + j] * inv;
        rows[gl][j + 64] = pooled[(size_t)g * HID + 64 + j] * inv;
        __syncthreads();
        float z = b1;
        #pragma unroll 8
        for (int c2 = 0; c2 < HID; ++c2) z += rows[gl][c2] * w1[c2 * 64 + j];
        z = fmaxf(z, 0.f);
        float p = z * w2;
        #pragma unroll
        for (int off = 32; off; off >>= 1) p += __shfl_down(p, off);
        if (j == 0) out[g] = p + fb2[0];
        __syncthreads();
    }
}

// ---------------- host ----------------
extern "C" void kernel_launch(void* const* d_in, const int* in_sizes, int n_in,
                              void* d_out, int out_size, void* d_ws, size_t ws_size,
                              hipStream_t stream)
{
    const float* x     = (const float*)d_in[0];
    const int*   ei    = (const int*)d_in[1];
    const int*   batch = (const int*)d_in[2];
    const float* W1  = (const float*)d_in[3];
    const float* as1 = (const float*)d_in[4];
    const float* ad1 = (const float*)d_in[5];
    const float* g1  = (const float*)d_in[7];
    const float* be1 = (const float*)d_in[8];
    const float* W2  = (const float*)d_in[9];
    const float* as2 = (const float*)d_in[10];
    const float* ad2 = (const float*)d_in[11];
    const float* g2  = (const float*)d_in[13];
    const float* be2 = (const float*)d_in[14];
    const float* W3  = (const float*)d_in[15];
    const float* as3 = (const float*)d_in[16];
    const float* ad3 = (const float*)d_in[17];
    const float* g3  = (const float*)d_in[19];
    const float* be3 = (const float*)d_in[20];
    const float* fw1 = (const float*)d_in[21];
    const float* fb1 = (const float*)d_in[22];
    const float* fw2 = (const float*)d_in[23];
    const float* fb2 = (const float*)d_in[24];
    float* out = (float*)d_out;

    // ---- ws layout ----
    ushort* Hb  = (ushort*)d_ws;                       // [N][128] bf16 GEMM output
    ushort* Bh  = Hb  + (size_t)N_NODES * HID;         // [N][128] bf16 aggregated
    ushort* Wt1 = Bh  + (size_t)N_NODES * HID + 128 * 128;  // pad: gemm reads OOB rows
    ushort* Wt2 = Wt1 + 128 * 32;                      // [128][128]
    ushort* Wt3 = Wt2 + 128 * 128;
    float* als    = (float*)(Wt3 + 128 * 128);
    float* ald    = als + (size_t)N_NODES * 4;
    float* sums1  = ald + (size_t)N_NODES * 4;         // 3 x [NSLICE][256]
    float* sums2  = sums1 + NSLICE * 256;
    float* sums3  = sums2 + NSLICE * 256;
    float* pooled = sums3 + NSLICE * 256;
    float* cnt    = pooled + (size_t)NGRAPH * HID;     // pooled+cnt contiguous
    int*   rowptr = (int*)(cnt + NGRAPH);
    int*   counts = rowptr + (N_NODES + 1);
    int*   cursor = counts + N_NODES;
    int*   bsum   = cursor + N_NODES;
    int*   psrc   = bsum + 512;

    auto cdiv = [](int a, int b) { return (a + b - 1) / b; };

    // ---- fused setup (weight converts + zero-inits, one dispatch) ----
    setup_kernel<<<cdiv(SETUP_TOT, 256), 256, 0, stream>>>(
        W1, W2, W3, Wt1, Wt2, Wt3, sums1, counts, pooled);

    // ---- CSR build (once) ----
    hist_kernel<<<cdiv(N_ETOT, 256), 256, 0, stream>>>(ei, counts);
    scanA_kernel<<<NBLK_SCAN, 256, 0, stream>>>(counts, rowptr, bsum);
    scanC_kernel<<<NBLK_SCAN, 256, 0, stream>>>(rowptr, bsum, cursor);
    scatter_kernel<<<cdiv(N_ETOT, 256), 256, 0, stream>>>(ei, cursor, psrc);

    const int ggrid = cdiv(N_NODES, 64);   // 1563 blocks (64 rows/block, 16/wave)
    const int agrid = N_NODES / 8;   // 12500, exact (8 nodes per block, 2 per wave)

    // ---- layer 1: K=32 (padded), A direct from f32 x, 4 heads ----
    mfma_gemm_kernel<32, false, 4, true><<<ggrid, 256, 0, stream>>>(
        nullptr, x, Wt1, nullptr, nullptr, nullptr, as1, ad1, Hb, als, ald, N_NODES);
    agg_kernel<4><<<agrid, 256, 0, stream>>>(Hb, als, ald, rowptr, psrc, Bh);
    bn_stats_kernel<<<STATS_BLOCKS, 256, 0, stream>>>(Bh, sums1);

    // ---- layer 2: K=128, BN(sums1,g1,be1) folded, 4 heads ----
    mfma_gemm_kernel<128, true, 4, false><<<ggrid, 256, 0, stream>>>(
        Bh, nullptr, Wt2, sums1, g1, be1, as2, ad2, Hb, als, ald, N_NODES);
    agg_kernel<4><<<agrid, 256, 0, stream>>>(Hb, als, ald, rowptr, psrc, Bh);
    bn_stats_kernel<<<STATS_BLOCKS, 256, 0, stream>>>(Bh, sums2);

    // ---- layer 3: K=128, BN(sums2,g2,be2) folded, 1 head ----
    mfma_gemm_kernel<128, true, 1, false><<<ggrid, 256, 0, stream>>>(
        Bh, nullptr, Wt3, sums2, g2, be2, as3, ad3, Hb, als, ald, N_NODES);
    agg_kernel<1><<<agrid, 256, 0, stream>>>(Hb, als, ald, rowptr, psrc, Bh);
    bn_stats_kernel<<<STATS_BLOCKS, 256, 0, stream>>>(Bh, sums3);

    // ---- BN(sums3,g3,be3)+ReLU fused pool, then MLP ----
    bn_pool_kernel<<<cdiv(N_NODES, PNPB), 128, 0, stream>>>(
        Bh, sums3, g3, be3, batch, pooled, cnt);
    mlp_kernel<<<NGRAPH / 16, 256, 0, stream>>>(pooled, cnt, fw1, fb1, fw2, fb2, out);
}